// Round 7
// baseline (10371.777 us; speedup 1.0000x reference)
//
#include <hip/hip_runtime.h>

#define S_LEN 256
// ws float offsets — TOTAL 27,519,488 floats = 110.08 MB (unchanged)
#define GI_OFF     0u           // [256][2048][32]  x@Wih + bih + bhh, [s][col][n]
#define VAL_OFF    16777216u    // [256][32][256]   x@Wv + bv
#define KEY_OFF    18874368u    // [256][32][256]   unitnorm(x@Wk + bk)
#define HTA_OFF    20971520u    // [257][32][512]   h history, BATCH-MAJOR: slot t+1 = h_t, [n][d]
#define ROB_OFF    25182208u    // [257][32][256]   read_out full history, slot t+1 = ro_t
#define WAQT_OFF   27287552u    // [768][296] K-MAJOR fused action+query weights (coalesced matvec)
#define BAQ_OFF    27514880u    // [296] biases (padded 512)
#define LFLG_OFF   27515392u    // 128 LSTM flags (pod*32+c), stride 16 u32
#define TFLG_OFF   27517440u    // (unused — tape protocol removed)
#define WS_TOTAL   27519488u

typedef __attribute__((address_space(1))) const void glb_cv;
typedef __attribute__((address_space(3))) void lds_v;

// ---- agent-scope helpers ----
__device__ __forceinline__ void coh_st(float* p, float v) {
  __hip_atomic_store(p, v, __ATOMIC_RELAXED, __HIP_MEMORY_SCOPE_AGENT);
}
__device__ __forceinline__ unsigned coh_ldu(const unsigned* p) {
  return __hip_atomic_load(p, __ATOMIC_RELAXED, __HIP_MEMORY_SCOPE_AGENT);
}
// RELEASE flag store: full agent-scope release sequence (R0 fix — keep).
__device__ __forceinline__ void coh_stu_rel(unsigned* p, unsigned v) {
  __hip_atomic_store(p, v, __ATOMIC_RELEASE, __HIP_MEMORY_SCOPE_AGENT);
}
// Uncached (SC0|SC1 = LLC-coherent) direct-to-LDS 16B/lane load (R3, proven).
#define ASYNC_LD16(gsrc, ldst) \
  __builtin_amdgcn_global_load_lds((glb_cv*)(gsrc), (lds_v*)(ldst), 16, 0, 17)

// Wait until 32 pod flags >= tgt (wave 0 polls, 1 flag/lane, lanes>=32 duplicate)
__device__ __forceinline__ void wait_pod(const unsigned* f, int base, int tid, unsigned tgt) {
  if (tid < 64) {
    const unsigned* fp = f + (size_t)(base + (tid & 31)) * 16;
    while (true) {
      unsigned a = coh_ldu(fp);
      if (__all(a >= tgt)) break;
      __builtin_amdgcn_s_sleep(1);
    }
    asm volatile("" ::: "memory");   // nothing hoists above the spin
  }
}

// ---- parallel pre-pass: gi = x@Wih + bih + bhh ; values = x@Wv+bv ; keys_raw = x@Wk+bk ----
__global__ __launch_bounds__(256) void k_pre(const float* __restrict__ inp,
    const float* __restrict__ Wih, const float* __restrict__ bih, const float* __restrict__ bhh,
    const float* __restrict__ Wv, const float* __restrict__ bv,
    const float* __restrict__ Wk, const float* __restrict__ bk, float* __restrict__ ws)
{
  __shared__ __align__(16) float xs[256 * 32];
  const int s = blockIdx.x / 10, tile = blockIdx.x % 10;
  const int tid = threadIdx.x;
  const float* W; int C, c;
  if (tile < 8)       { W = Wih; C = 2048; c = tile * 256 + tid; }
  else if (tile == 8) { W = Wv;  C = 256;  c = tid; }
  else                { W = Wk;  C = 256;  c = tid; }

  float acc[32];
#pragma unroll
  for (int n = 0; n < 32; ++n) acc[n] = 0.f;

  for (int p = 0; p < 2; ++p) {
    __syncthreads();
    for (int w = 0; w < 32; ++w) {
      int i = tid + w * 256;
      int k = i & 255, n = i >> 8;
      float v = inp[s * 16384 + n * 512 + p * 256 + k];
      int pos = ((((n >> 2) + (k & 7)) & 7) << 2) | (n & 3);
      xs[k * 32 + pos] = v;
    }
    __syncthreads();
    const float* Wp = W + (size_t)(p * 256) * C + c;
#pragma unroll 8
    for (int kk = 0; kk < 256; ++kk) {
      float wv = Wp[(size_t)kk * C];
      const float4* row = (const float4*)(xs + kk * 32);
#pragma unroll
      for (int j = 0; j < 8; ++j) {
        float4 a = row[(j + (kk & 7)) & 7];
        acc[4 * j + 0] = fmaf(a.x, wv, acc[4 * j + 0]);
        acc[4 * j + 1] = fmaf(a.y, wv, acc[4 * j + 1]);
        acc[4 * j + 2] = fmaf(a.z, wv, acc[4 * j + 2]);
        acc[4 * j + 3] = fmaf(a.w, wv, acc[4 * j + 3]);
      }
    }
  }

  if (tile < 8) {
    float bb = bih[c] + bhh[c];
    float4* dst = (float4*)(ws + GI_OFF + (size_t)s * 65536 + (size_t)c * 32);
#pragma unroll
    for (int j = 0; j < 8; ++j)
      dst[j] = make_float4(acc[4 * j] + bb, acc[4 * j + 1] + bb, acc[4 * j + 2] + bb, acc[4 * j + 3] + bb);
  } else {
    unsigned base = (tile == 8) ? VAL_OFF : KEY_OFF;
    float bb = (tile == 8) ? bv[c] : bk[c];
#pragma unroll
    for (int n = 0; n < 32; ++n)
      ws[base + (size_t)s * 8192 + n * 256 + c] = acc[n] + bb;
  }
}

__global__ __launch_bounds__(256) void k_knorm(float* __restrict__ ws) {
  int b = blockIdx.x;
  int m = threadIdx.x;
  float* p = ws + KEY_OFF + (size_t)b * 256;
  float x = p[m];
  float ss = x * x;
#pragma unroll
  for (int off = 32; off > 0; off >>= 1) ss += __shfl_xor(ss, off, 64);
  p[m] = x / fmaxf(sqrtf(ss), 1e-12f);
}

// Build K-MAJOR fused action+query weight table WAQT_T[768][296] (+ biases BAQ[296]).
__global__ __launch_bounds__(256) void k_prep_waq(const float* __restrict__ Wa, const float* __restrict__ ba,
                                                  const float* __restrict__ Wq, const float* __restrict__ bq,
                                                  float* __restrict__ ws) {
  int o = blockIdx.x;                       // global output 0..295 (tp*74 + j)
  int k = blockIdx.y * 256 + threadIdx.x;   // 0..767
  int tp = o / 74, j = o - tp * 74;
  float v = (j < 10) ? Wa[k * 40 + tp * 10 + j] : Wq[k * 256 + tp * 64 + (j - 10)];
  ws[WAQT_OFF + (size_t)k * 296 + o] = v;
  if (k == 0) ws[BAQ_OFF + o] = (j < 10) ? ba[tp * 10 + j] : bq[tp * 64 + (j - 10)];
}

struct P1S { float hs[4096]; };       // 16 KB: LSTM pod's 8 h-rows, [n][512], linear
struct DT {                           // fused tape block: all 4 tapes of one batch
  float tape[4][32][64];              // 32 KB
  float tkey[4][32][64];              // 32 KB
  __align__(16) float har[768];       // [h(512) | ro_prev(256)]
  __align__(16) float scrq[3552];     // 888 float4 partials, idx (kc*74+q)*4+e
  float q[4][64];
  float act[4][12];
};
union __align__(16) SU { P1S p; DT d; };

// Plain launch, 160 blocks: 128 LSTM (4 pods x 32) + 32 fused tape (1/batch).
// Tape blocks have NO inter-block protocol: ro lives in LDS, ROB written with
// plain cached stores (consumed only by k_out_gemm after kernel end).
__global__ __launch_bounds__(256, 1) void nam_coop(
    const float* __restrict__ Whh, float* __restrict__ ws, float* __restrict__ out)
{
  __shared__ SU sm;
  const int blk = blockIdx.x, tid = threadIdx.x;
  unsigned* lflg = (unsigned*)(ws + LFLG_OFF);

  if (blk < 128) {
    // ============ LSTM block: pod = blk>>5 (8 batches), 16 dims x 4 gates (R3-R5, proven) ============
    const int pod = blk >> 5, c = blk & 31;
    const int ks = tid & 15, cq = tid >> 4;
    const int dg = c * 16 + cq;
    float wG0[32], wG1[32], wG2[32], wG3[32];
#pragma unroll
    for (int j = 0; j < 32; ++j) {
      const float* wr = Whh + (size_t)(j * 16 + ks) * 2048 + dg;
      wG0[j] = wr[0]; wG1[j] = wr[512]; wG2[j] = wr[1024]; wG3[j] = wr[1536];
    }
    const bool fin = (ks == 0);
    float creg[8];
#pragma unroll
    for (int e = 0; e < 8; ++e) creg[e] = 0.f;

    const int wv = tid >> 6, ln = tid & 63;

    for (int t = 0; t < S_LEN; ++t) {
      float gi[32];
      if (fin) {
        const float* gb = ws + GI_OFF + (size_t)t * 65536 + (size_t)dg * 32 + pod * 8;
#pragma unroll
        for (int g = 0; g < 4; ++g) {
          float4 lo = *(const float4*)(gb + (size_t)g * 16384);
          float4 hi = *(const float4*)(gb + (size_t)g * 16384 + 4);
          gi[g * 8 + 0] = lo.x; gi[g * 8 + 1] = lo.y; gi[g * 8 + 2] = lo.z; gi[g * 8 + 3] = lo.w;
          gi[g * 8 + 4] = hi.x; gi[g * 8 + 5] = hi.y; gi[g * 8 + 6] = hi.z; gi[g * 8 + 7] = hi.w;
        }
      }
      if (t > 0) wait_pod(lflg, pod * 32, tid, (unsigned)t);
      __syncthreads();
      {
        const float* hsrc = ws + HTA_OFF + (size_t)t * 16384 + (size_t)pod * 4096
                          + (size_t)wv * 1024 + (size_t)ln * 4;
#pragma unroll
        for (int i = 0; i < 4; ++i)
          ASYNC_LD16(hsrc + i * 256, &sm.p.hs[wv * 1024 + i * 256]);
      }
      __syncthreads();   // drains vmcnt (async LDS loads)
      float a0[8], a1[8], a2[8], a3[8];
#pragma unroll
      for (int e = 0; e < 8; ++e) { a0[e] = 0.f; a1[e] = 0.f; a2[e] = 0.f; a3[e] = 0.f; }
#pragma unroll
      for (int j = 0; j < 32; ++j) {
        const int kk = j * 16 + ks;
        float w0 = wG0[j], w1 = wG1[j], w2 = wG2[j], w3 = wG3[j];
#pragma unroll
        for (int e = 0; e < 8; ++e) {
          float hv = sm.p.hs[e * 512 + kk];
          a0[e] = fmaf(hv, w0, a0[e]);
          a1[e] = fmaf(hv, w1, a1[e]);
          a2[e] = fmaf(hv, w2, a2[e]);
          a3[e] = fmaf(hv, w3, a3[e]);
        }
      }
#pragma unroll
      for (int e = 0; e < 8; ++e) {
        float v0 = a0[e], v1 = a1[e], v2 = a2[e], v3 = a3[e];
        v0 += __shfl_down(v0, 8, 16); v1 += __shfl_down(v1, 8, 16);
        v2 += __shfl_down(v2, 8, 16); v3 += __shfl_down(v3, 8, 16);
        v0 += __shfl_down(v0, 4, 16); v1 += __shfl_down(v1, 4, 16);
        v2 += __shfl_down(v2, 4, 16); v3 += __shfl_down(v3, 4, 16);
        v0 += __shfl_down(v0, 2, 16); v1 += __shfl_down(v1, 2, 16);
        v2 += __shfl_down(v2, 2, 16); v3 += __shfl_down(v3, 2, 16);
        v0 += __shfl_down(v0, 1, 16); v1 += __shfl_down(v1, 1, 16);
        v2 += __shfl_down(v2, 1, 16); v3 += __shfl_down(v3, 1, 16);
        a0[e] = v0; a1[e] = v1; a2[e] = v2; a3[e] = v3;
      }
      if (fin) {
        float* hdst = ws + HTA_OFF + (size_t)(t + 1) * 16384 + (size_t)pod * 4096 + dg;
#pragma unroll
        for (int e = 0; e < 8; ++e) {
          float gvi = a0[e] + gi[e];
          float gvf = a1[e] + gi[8 + e];
          float gvg = a2[e] + gi[16 + e];
          float gvo = a3[e] + gi[24 + e];
          float si = 1.f / (1.f + expf(-gvi));
          float sf = 1.f / (1.f + expf(-gvf));
          float so = 1.f / (1.f + expf(-gvo));
          float cn = sf * creg[e] + si * tanhf(gvg);
          float hn = so * tanhf(cn);
          creg[e] = cn;
          coh_st(hdst + (size_t)e * 512, hn);
        }
      }
      __syncthreads();   // h stores vmcnt-drained before flag
      if (tid == 0) coh_stu_rel(lflg + blk * 16, (unsigned)(t + 1));
    }
  } else {
    // ============ fused tape block: ALL 4 tapes of batch n, wave w = tape tpp (R4, proven) ============
    const int n = blk - 128;
    const int w = tid >> 6, c = tid & 63;
    const int lpodbase = (n >> 3) * 32;

    for (int i = tid; i < 8192; i += 256) {
      ((float*)sm.d.tape)[i] = 0.f;
      ((float*)sm.d.tkey)[i] = 0.f;
    }
    sm.d.har[512 + tid] = 0.f;                 // ro_{-1} = 0
    float wpl = (c == 0) ? 1.f : 0.f, rpl = wpl;  // pos state in registers
    __syncthreads();

    for (int tau = 0; tau < S_LEN; ++tau) {
      // flag-independent prefetch (registers, cached)
      float vreg = ws[VAL_OFF + (size_t)tau * 8192 + n * 256 + tid];
      float kreg = ws[KEY_OFF + (size_t)tau * 8192 + n * 256 + tid];
      // wait: h_tau ready (own pod's 32 flags)
      wait_pod(lflg, lpodbase, tid, (unsigned)(tau + 1));
      __syncthreads();   // gate all waves; fences prev step's har/ro LDS writes
      // stage h_tau (contiguous 2KB) via uncached direct-to-LDS
      if (w == 0) {
        const float* hb = ws + HTA_OFF + (size_t)(tau + 1) * 16384 + (size_t)n * 512 + (size_t)c * 4;
        ASYNC_LD16(hb,       &sm.d.har[0]);
        ASYNC_LD16(hb + 256, &sm.d.har[256]);
      }
      __syncthreads();   // drains async vmcnt
      // fused action+query matvec, K-MAJOR coalesced: 888 tasks = (kc 0..11) x (q 0..73)
      for (int t = tid; t < 888; t += 256) {
        const int kc = t / 74, q = t - kc * 74;
        const float* wp = ws + WAQT_OFF + (size_t)(kc * 64) * 296 + q * 4;
        const float* hp = sm.d.har + kc * 64;
        float4 acc = make_float4(0.f, 0.f, 0.f, 0.f);
#pragma unroll 8
        for (int kk = 0; kk < 64; ++kk) {
          float4 w4 = *(const float4*)(wp + (size_t)kk * 296);
          float h = hp[kk];
          acc.x = fmaf(w4.x, h, acc.x);
          acc.y = fmaf(w4.y, h, acc.y);
          acc.z = fmaf(w4.z, h, acc.z);
          acc.w = fmaf(w4.w, h, acc.w);
        }
        ((float4*)sm.d.scrq)[t] = acc;
      }
      __syncthreads();
      // reduce 12 k-chunks + bias -> act / q  (ALL 296 outputs — R6 bug was tid<296 on 256 threads)
      for (int o = tid; o < 296; o += 256) {
        int q2 = o >> 2, e = o & 3;
        float s = 0.f;
#pragma unroll
        for (int kc = 0; kc < 12; ++kc) s += sm.d.scrq[(kc * 74 + q2) * 4 + e];
        float val = s + ws[BAQ_OFF + o];
        int tp2 = o / 74, j2 = o - tp2 * 74;
        if (j2 < 10) sm.d.act[tp2][j2] = val; else sm.d.q[tp2][j2 - 10] = val;
      }
      __syncthreads();
      // per-wave (per-tape) scalars: softmaxes + gates (lane-redundant)
      float rd0, rd1, rd2, rd3, wd0, wd1, wd2, wd3, rw0, rw1;
      {
        float a0 = sm.d.act[w][0], a1 = sm.d.act[w][1], a2 = sm.d.act[w][2], a3 = sm.d.act[w][3];
        float mx = fmaxf(fmaxf(a0, a1), fmaxf(a2, a3));
        float e0 = expf(a0 - mx), e1 = expf(a1 - mx), e2 = expf(a2 - mx), e3 = expf(a3 - mx);
        float inv = 1.f / (e0 + e1 + e2 + e3);
        rd0 = e0 * inv; rd1 = e1 * inv; rd2 = e2 * inv; rd3 = e3 * inv;
        a0 = sm.d.act[w][4]; a1 = sm.d.act[w][5]; a2 = sm.d.act[w][6]; a3 = sm.d.act[w][7];
        mx = fmaxf(fmaxf(a0, a1), fmaxf(a2, a3));
        e0 = expf(a0 - mx); e1 = expf(a1 - mx); e2 = expf(a2 - mx); e3 = expf(a3 - mx);
        inv = 1.f / (e0 + e1 + e2 + e3);
        wd0 = e0 * inv; wd1 = e1 * inv; wd2 = e2 * inv; wd3 = e3 * inv;
        rw0 = 1.f / (1.f + expf(-sm.d.act[w][8]));
        rw1 = 1.f / (1.f + expf(-sm.d.act[w][9]));
      }
      float qc = sm.d.q[w][c];
      // pass 1: oldval/oldkey (wpos broadcast via shfl)
      float pv = 0.f, pk = 0.f;
#pragma unroll
      for (int l = 0; l < 32; ++l) {
        float wp = __shfl(wpl, l, 64);
        pv = fmaf(sm.d.tape[w][l][c], wp, pv);
        pk = fmaf(sm.d.tkey[w][l][c], wp, pk);
      }
      float dvc = (vreg - pv) * rw1;
      float dkc = (kreg - pk) * rw1;
      // pass 2: tape/tkey update + read_out + jpos (64-lane butterfly per l)
      float pr = 0.f, jpreg = 0.f;
#pragma unroll
      for (int l = 0; l < 32; ++l) {
        float wp = __shfl(wpl, l, 64);
        float rp = __shfl(rpl, l, 64);
        float tv = fmaf(wp, dvc, sm.d.tape[w][l][c]);
        float tk = fmaf(wp, dkc, sm.d.tkey[w][l][c]);
        sm.d.tape[w][l][c] = tv;
        sm.d.tkey[w][l][c] = tk;
        pr = fmaf(tv, rp, pr);
        float s = tk * qc;
        s += __shfl_xor(s, 1, 64);  s += __shfl_xor(s, 2, 64);
        s += __shfl_xor(s, 4, 64);  s += __shfl_xor(s, 8, 64);
        s += __shfl_xor(s, 16, 64); s += __shfl_xor(s, 32, 64);
        if (c == l) jpreg = s;
      }
      float rov = pr * rw0;
      // jpos norm over 32 slots (lanes>=32 hold 0)
      float ss = jpreg * jpreg;
      ss += __shfl_xor(ss, 1, 64);  ss += __shfl_xor(ss, 2, 64);
      ss += __shfl_xor(ss, 4, 64);  ss += __shfl_xor(ss, 8, 64);
      ss += __shfl_xor(ss, 16, 64); ss += __shfl_xor(ss, 32, 64);
      float jn = jpreg / fmaxf(sqrtf(ss), 1e-12f);
      // pos update (register state; shfl sources always lanes<32)
      {
        float prv = __shfl(rpl, (c + 1) & 31, 64);
        float nxt = __shfl(rpl, (c + 31) & 31, 64);
        float wnew = prv * wd0 + wpl * wd1 + nxt * wd2 + jn * wd3;
        float rnew = prv * rd0 + rpl * rd1 + nxt * rd2 + jn * rd3;
        wpl = wnew; rpl = rnew;
      }
      // publish read_out: LDS (next step's har) + plain cached ROB store
      sm.d.har[512 + w * 64 + c] = rov;
      ws[ROB_OFF + (size_t)(tau + 1) * 8192 + n * 256 + w * 64 + c] = rov;
    }
    // final tape write-out (plain stores)
    for (int i = tid; i < 8192; i += 256) {
      int tp2 = i >> 11, l = (i >> 6) & 31, cc = i & 63;
      out[4194304 + (size_t)(l * 32 + n) * 256 + tp2 * 64 + cc] = sm.d.tape[tp2][l][cc];
    }
  }
}

// out[s][n][d] = sum_m ROB[s+1][n][m] * Wo[m][d] + bo[d]; LDS-transposed ro tile
__global__ __launch_bounds__(256) void k_out_gemm(const float* __restrict__ rob, const float* __restrict__ Wo,
                                                  const float* __restrict__ bo, float* __restrict__ out) {
  __shared__ __align__(16) float ro[256 * 32];   // [m][n], XOR-swizzled float4 chunks over n
  int s = blockIdx.x >> 1, dh = blockIdx.x & 1;
  int d = dh * 256 + threadIdx.x;
  const int tid = threadIdx.x;
  const float* src = rob + (size_t)(s + 1) * 8192;   // slot s+1 = read_outs step s
  for (int w = 0; w < 32; ++w) {
    int idx = tid + w * 256;                 // idx = n*256 + m
    int n = idx >> 8, m = idx & 255;
    float v = src[idx];
    ro[m * 32 + ((((n >> 2) ^ (m & 7)) << 2) | (n & 3))] = v;
  }
  __syncthreads();
  float acc[32];
#pragma unroll
  for (int n = 0; n < 32; ++n) acc[n] = 0.f;
  for (int m = 0; m < 256; ++m) {
    float w = Wo[m * 512 + d];
    const float4* rc = (const float4*)(ro + m * 32);
#pragma unroll
    for (int j = 0; j < 8; ++j) {
      float4 r4 = rc[j ^ (m & 7)];
      acc[4 * j + 0] = fmaf(r4.x, w, acc[4 * j + 0]);
      acc[4 * j + 1] = fmaf(r4.y, w, acc[4 * j + 1]);
      acc[4 * j + 2] = fmaf(r4.z, w, acc[4 * j + 2]);
      acc[4 * j + 3] = fmaf(r4.w, w, acc[4 * j + 3]);
    }
  }
  float bd = bo[d];
#pragma unroll
  for (int n = 0; n < 32; ++n) out[(size_t)(s * 32 + n) * 512 + d] = acc[n] + bd;
}

extern "C" void kernel_launch(void* const* d_in, const int* in_sizes, int n_in,
                              void* d_out, int out_size, void* d_ws, size_t ws_size,
                              hipStream_t stream) {
  const float* inp = (const float*)d_in[0];
  const float* Wih = (const float*)d_in[1];
  const float* Whh = (const float*)d_in[2];
  const float* bih = (const float*)d_in[3];
  const float* bhh = (const float*)d_in[4];
  const float* Wa  = (const float*)d_in[5];
  const float* ba  = (const float*)d_in[6];
  const float* Wv  = (const float*)d_in[7];
  const float* bv  = (const float*)d_in[8];
  const float* Wk  = (const float*)d_in[9];
  const float* bk  = (const float*)d_in[10];
  const float* Wq  = (const float*)d_in[11];
  const float* bq  = (const float*)d_in[12];
  const float* Wo  = (const float*)d_in[13];
  const float* bo  = (const float*)d_in[14];
  float* ws = (float*)d_ws;
  float* out = (float*)d_out;

  hipMemsetAsync(ws + HTA_OFF, 0, 16384 * sizeof(float), stream);    // h_{-1} slot
  hipMemsetAsync(ws + ROB_OFF, 0, 8192 * sizeof(float), stream);     // ro_{-1} slot
  hipMemsetAsync(ws + LFLG_OFF, 0, 4096 * sizeof(unsigned), stream); // LFLG (+legacy TFLG)
  k_prep_waq<<<dim3(296, 3), 256, 0, stream>>>(Wa, ba, Wq, bq, ws);
  k_pre<<<2560, 256, 0, stream>>>(inp, Wih, bih, bhh, Wv, bv, Wk, bk, ws);
  k_knorm<<<8192, 256, 0, stream>>>(ws);

  // 160 blocks: 128 LSTM + 32 fused-tape (no tape protocol).
  nam_coop<<<dim3(160), dim3(256), 0, stream>>>(Whh, ws, out);

  k_out_gemm<<<512, 256, 0, stream>>>(ws + ROB_OFF, Wo, bo, out);
}

// Round 9
// 3268.397 us; speedup vs baseline: 3.1734x; 3.1734x over previous
//
#include <hip/hip_runtime.h>

#define S_LEN 256
// ws float offsets — TOTAL 27,519,488 floats = 110.08 MB (unchanged)
#define GI_OFF     0u           // [256][2048][32]  x@Wih + bih + bhh, [s][col][n]
#define VAL_OFF    16777216u    // [256][32][256]   x@Wv + bv
#define KEY_OFF    18874368u    // [256][32][256]   unitnorm(x@Wk + bk)
#define HTA_OFF    20971520u    // [257][32][512]   h history, BATCH-MAJOR: slot t+1 = h_t, [n][d]
#define ROB_OFF    25182208u    // [257][32][256]   read_out full history, slot t+1 = ro_t
#define WAQT_OFF   27287552u    // [768][296] K-MAJOR fused action+query weights fp32
#define BAQ_OFF    27514880u    // [296] biases (padded 512)
#define LFLG_OFF   27515392u    // 128 LSTM flags (pod*32+c), stride 16 u32
#define TFLG_OFF   27517440u    // 128 tape flags, stride 16 u32
#define WS_TOTAL   27519488u

typedef __attribute__((address_space(1))) const void glb_cv;
typedef __attribute__((address_space(3))) void lds_v;

// ---- agent-scope helpers ----
__device__ __forceinline__ void coh_st(float* p, float v) {
  __hip_atomic_store(p, v, __ATOMIC_RELAXED, __HIP_MEMORY_SCOPE_AGENT);
}
__device__ __forceinline__ unsigned coh_ldu(const unsigned* p) {
  return __hip_atomic_load(p, __ATOMIC_RELAXED, __HIP_MEMORY_SCOPE_AGENT);
}
// RELEASE flag store: full agent-scope release sequence (R0 fix — keep).
__device__ __forceinline__ void coh_stu_rel(unsigned* p, unsigned v) {
  __hip_atomic_store(p, v, __ATOMIC_RELEASE, __HIP_MEMORY_SCOPE_AGENT);
}
// Uncached (SC0|SC1 = LLC-coherent) direct-to-LDS 16B/lane load (R3, proven).
#define ASYNC_LD16(gsrc, ldst) \
  __builtin_amdgcn_global_load_lds((glb_cv*)(gsrc), (lds_v*)(ldst), 16, 0, 17)

// Wait until 32 pod flags >= tgt (wave 0 polls, 1 flag/lane, lanes>=32 duplicate)
__device__ __forceinline__ void wait_pod(const unsigned* f, int base, int tid, unsigned tgt) {
  if (tid < 64) {
    const unsigned* fp = f + (size_t)(base + (tid & 31)) * 16;
    while (true) {
      unsigned a = coh_ldu(fp);
      if (__all(a >= tgt)) break;
      __builtin_amdgcn_s_sleep(1);
    }
    asm volatile("" ::: "memory");   // nothing hoists above the spin
  }
}

// ---- parallel pre-pass: gi = x@Wih + bih + bhh ; values = x@Wv+bv ; keys_raw = x@Wk+bk ----
__global__ __launch_bounds__(256) void k_pre(const float* __restrict__ inp,
    const float* __restrict__ Wih, const float* __restrict__ bih, const float* __restrict__ bhh,
    const float* __restrict__ Wv, const float* __restrict__ bv,
    const float* __restrict__ Wk, const float* __restrict__ bk, float* __restrict__ ws)
{
  __shared__ __align__(16) float xs[256 * 32];
  const int s = blockIdx.x / 10, tile = blockIdx.x % 10;
  const int tid = threadIdx.x;
  const float* W; int C, c;
  if (tile < 8)       { W = Wih; C = 2048; c = tile * 256 + tid; }
  else if (tile == 8) { W = Wv;  C = 256;  c = tid; }
  else                { W = Wk;  C = 256;  c = tid; }

  float acc[32];
#pragma unroll
  for (int n = 0; n < 32; ++n) acc[n] = 0.f;

  for (int p = 0; p < 2; ++p) {
    __syncthreads();
    for (int w = 0; w < 32; ++w) {
      int i = tid + w * 256;
      int k = i & 255, n = i >> 8;
      float v = inp[s * 16384 + n * 512 + p * 256 + k];
      int pos = ((((n >> 2) + (k & 7)) & 7) << 2) | (n & 3);
      xs[k * 32 + pos] = v;
    }
    __syncthreads();
    const float* Wp = W + (size_t)(p * 256) * C + c;
#pragma unroll 8
    for (int kk = 0; kk < 256; ++kk) {
      float wv = Wp[(size_t)kk * C];
      const float4* row = (const float4*)(xs + kk * 32);
#pragma unroll
      for (int j = 0; j < 8; ++j) {
        float4 a = row[(j + (kk & 7)) & 7];
        acc[4 * j + 0] = fmaf(a.x, wv, acc[4 * j + 0]);
        acc[4 * j + 1] = fmaf(a.y, wv, acc[4 * j + 1]);
        acc[4 * j + 2] = fmaf(a.z, wv, acc[4 * j + 2]);
        acc[4 * j + 3] = fmaf(a.w, wv, acc[4 * j + 3]);
      }
    }
  }

  if (tile < 8) {
    float bb = bih[c] + bhh[c];
    float4* dst = (float4*)(ws + GI_OFF + (size_t)s * 65536 + (size_t)c * 32);
#pragma unroll
    for (int j = 0; j < 8; ++j)
      dst[j] = make_float4(acc[4 * j] + bb, acc[4 * j + 1] + bb, acc[4 * j + 2] + bb, acc[4 * j + 3] + bb);
  } else {
    unsigned base = (tile == 8) ? VAL_OFF : KEY_OFF;
    float bb = (tile == 8) ? bv[c] : bk[c];
#pragma unroll
    for (int n = 0; n < 32; ++n)
      ws[base + (size_t)s * 8192 + n * 256 + c] = acc[n] + bb;
  }
}

__global__ __launch_bounds__(256) void k_knorm(float* __restrict__ ws) {
  int b = blockIdx.x;
  int m = threadIdx.x;
  float* p = ws + KEY_OFF + (size_t)b * 256;
  float x = p[m];
  float ss = x * x;
#pragma unroll
  for (int off = 32; off > 0; off >>= 1) ss += __shfl_xor(ss, off, 64);
  p[m] = x / fmaxf(sqrtf(ss), 1e-12f);
}

// Build K-MAJOR fused action+query weight table WAQT_T[768][296] (+ biases BAQ[296]).
__global__ __launch_bounds__(256) void k_prep_waq(const float* __restrict__ Wa, const float* __restrict__ ba,
                                                  const float* __restrict__ Wq, const float* __restrict__ bq,
                                                  float* __restrict__ ws) {
  int o = blockIdx.x;                       // global output 0..295 (tp*74 + j)
  int k = blockIdx.y * 256 + threadIdx.x;   // 0..767
  int tp = o / 74, j = o - tp * 74;
  float v = (j < 10) ? Wa[k * 40 + tp * 10 + j] : Wq[k * 256 + tp * 64 + (j - 10)];
  ws[WAQT_OFF + (size_t)k * 296 + o] = v;
  if (k == 0) ws[BAQ_OFF + o] = (j < 10) ? ba[tp * 10 + j] : bq[tp * 64 + (j - 10)];
}

struct P1S { float hs[4096]; };       // 16 KB: LSTM pod's 8 h-rows, [n][512], linear
struct DS {
  float tape[32][64]; float tkey[32][64];
  float rpos[32]; float wpos[32];
  __align__(16) float har[768];
  float act[12]; float q[64]; float v[64]; float kr[64];
  float dv[64]; float dk[64];
  float scrA[256]; float scrB[256];
  float scrq[448];                    // 222 threads x 2 outputs (matvec partials)
  float norm;
};
union __align__(16) SU { P1S p; DS d; };

// Plain (non-cooperative) launch: flag-spin protocol only; all 256 blocks co-resident.
// R5 topology: 128 LSTM (4 pods x 32) + 128 tape (n,tp). NEW: tape's action+query
// weights are REGISTER-STATIONARY (128 float2/thread, fp32 exact) — loaded once in
// the prologue, zero per-step weight traffic (the serial-path elephant since R0).
__global__ __launch_bounds__(256, 1) void nam_coop(
    const float* __restrict__ Whh, float* __restrict__ ws, float* __restrict__ out)
{
  __shared__ SU sm;
  const int blk = blockIdx.x, tid = threadIdx.x;
  unsigned* lflg = (unsigned*)(ws + LFLG_OFF);
  unsigned* tflg = (unsigned*)(ws + TFLG_OFF);

  if (blk < 128) {
    // ============ LSTM block: pod = blk>>5 (8 batches), 16 dims x 4 gates (R3-R5, proven) ============
    const int pod = blk >> 5, c = blk & 31;
    const int ks = tid & 15, cq = tid >> 4;
    const int dg = c * 16 + cq;
    float wG0[32], wG1[32], wG2[32], wG3[32];
#pragma unroll
    for (int j = 0; j < 32; ++j) {
      const float* wr = Whh + (size_t)(j * 16 + ks) * 2048 + dg;
      wG0[j] = wr[0]; wG1[j] = wr[512]; wG2[j] = wr[1024]; wG3[j] = wr[1536];
    }
    const bool fin = (ks == 0);
    float creg[8];
#pragma unroll
    for (int e = 0; e < 8; ++e) creg[e] = 0.f;

    const int wv = tid >> 6, ln = tid & 63;

    for (int t = 0; t < S_LEN; ++t) {
      float gi[32];
      if (fin) {
        const float* gb = ws + GI_OFF + (size_t)t * 65536 + (size_t)dg * 32 + pod * 8;
#pragma unroll
        for (int g = 0; g < 4; ++g) {
          float4 lo = *(const float4*)(gb + (size_t)g * 16384);
          float4 hi = *(const float4*)(gb + (size_t)g * 16384 + 4);
          gi[g * 8 + 0] = lo.x; gi[g * 8 + 1] = lo.y; gi[g * 8 + 2] = lo.z; gi[g * 8 + 3] = lo.w;
          gi[g * 8 + 4] = hi.x; gi[g * 8 + 5] = hi.y; gi[g * 8 + 6] = hi.z; gi[g * 8 + 7] = hi.w;
        }
      }
      if (t > 0) wait_pod(lflg, pod * 32, tid, (unsigned)t);
      __syncthreads();
      {
        const float* hsrc = ws + HTA_OFF + (size_t)t * 16384 + (size_t)pod * 4096
                          + (size_t)wv * 1024 + (size_t)ln * 4;
#pragma unroll
        for (int i = 0; i < 4; ++i)
          ASYNC_LD16(hsrc + i * 256, &sm.p.hs[wv * 1024 + i * 256]);
      }
      __syncthreads();   // drains vmcnt (async LDS loads)
      float a0[8], a1[8], a2[8], a3[8];
#pragma unroll
      for (int e = 0; e < 8; ++e) { a0[e] = 0.f; a1[e] = 0.f; a2[e] = 0.f; a3[e] = 0.f; }
#pragma unroll
      for (int j = 0; j < 32; ++j) {
        const int kk = j * 16 + ks;
        float w0 = wG0[j], w1 = wG1[j], w2 = wG2[j], w3 = wG3[j];
#pragma unroll
        for (int e = 0; e < 8; ++e) {
          float hv = sm.p.hs[e * 512 + kk];
          a0[e] = fmaf(hv, w0, a0[e]);
          a1[e] = fmaf(hv, w1, a1[e]);
          a2[e] = fmaf(hv, w2, a2[e]);
          a3[e] = fmaf(hv, w3, a3[e]);
        }
      }
#pragma unroll
      for (int e = 0; e < 8; ++e) {
        float v0 = a0[e], v1 = a1[e], v2 = a2[e], v3 = a3[e];
        v0 += __shfl_down(v0, 8, 16); v1 += __shfl_down(v1, 8, 16);
        v2 += __shfl_down(v2, 8, 16); v3 += __shfl_down(v3, 8, 16);
        v0 += __shfl_down(v0, 4, 16); v1 += __shfl_down(v1, 4, 16);
        v2 += __shfl_down(v2, 4, 16); v3 += __shfl_down(v3, 4, 16);
        v0 += __shfl_down(v0, 2, 16); v1 += __shfl_down(v1, 2, 16);
        v2 += __shfl_down(v2, 2, 16); v3 += __shfl_down(v3, 2, 16);
        v0 += __shfl_down(v0, 1, 16); v1 += __shfl_down(v1, 1, 16);
        v2 += __shfl_down(v2, 1, 16); v3 += __shfl_down(v3, 1, 16);
        a0[e] = v0; a1[e] = v1; a2[e] = v2; a3[e] = v3;
      }
      if (fin) {
        float* hdst = ws + HTA_OFF + (size_t)(t + 1) * 16384 + (size_t)pod * 4096 + dg;
#pragma unroll
        for (int e = 0; e < 8; ++e) {
          float gvi = a0[e] + gi[e];
          float gvf = a1[e] + gi[8 + e];
          float gvg = a2[e] + gi[16 + e];
          float gvo = a3[e] + gi[24 + e];
          float si = 1.f / (1.f + expf(-gvi));
          float sf = 1.f / (1.f + expf(-gvf));
          float so = 1.f / (1.f + expf(-gvo));
          float cn = sf * creg[e] + si * tanhf(gvg);
          float hn = so * tanhf(cn);
          creg[e] = cn;
          coh_st(hdst + (size_t)e * 512, hn);
        }
      }
      __syncthreads();   // h stores vmcnt-drained before flag
      if (tid == 0) coh_stu_rel(lflg + blk * 16, (unsigned)(t + 1));
    }
  } else {
    // ============ tape block: one (n, tp) group (R5 structure, REG-stationary weights) ============
    const int g = blk - 128, n = g >> 2, tpp = g & 3;
    const int lpodbase = (n >> 3) * 32;
    // matvec task decomposition: tid = s6*37 + p37 (222 active threads)
    const int p37 = tid % 37, s6 = tid / 37;
    // prologue: load this thread's 2-output x 128-K weight slab into registers (fp32, once)
    float2 wreg[128];
    if (tid < 222) {
      const float* wb = ws + WAQT_OFF + (size_t)(s6 * 128) * 296 + tpp * 74 + 2 * p37;
#pragma unroll
      for (int r = 0; r < 128; ++r)
        wreg[r] = *(const float2*)(wb + (size_t)r * 296);
    }
    for (int i = tid; i < 2048; i += 256) { int l = i >> 6, c = i & 63; sm.d.tape[l][c] = 0.f; sm.d.tkey[l][c] = 0.f; }
    if (tid < 32) { sm.d.rpos[tid] = (tid == 0) ? 1.f : 0.f; sm.d.wpos[tid] = (tid == 0) ? 1.f : 0.f; }
    __syncthreads();

    const int wv = tid >> 6, ln = tid & 63;

    for (int tau = 0; tau < S_LEN; ++tau) {
      // flag-independent prefetch (plain cached)
      float vreg = 0.f, kreg = 0.f;
      if (tid < 64)        vreg = ws[VAL_OFF + (size_t)tau * 8192 + n * 256 + tpp * 64 + tid];
      else if (tid < 128)  kreg = ws[KEY_OFF + (size_t)tau * 8192 + n * 256 + tpp * 64 + (tid - 64)];
      // wait: h_tau ready (own pod's 32 flags), sibling ro_{tau-1} ready (4 tape flags)
      wait_pod(lflg, lpodbase, tid, (unsigned)(tau + 1));
      if (tid < 64 && tau > 0) {
        unsigned tgt2 = (unsigned)tau;
        while (true) {
          unsigned a = (tid < 4) ? coh_ldu(tflg + (n * 4 + tid) * 16) : tgt2;
          if (__all(a >= tgt2)) break;
          __builtin_amdgcn_s_sleep(1);
        }
        asm volatile("" ::: "memory");
      }
      __syncthreads();
      // stage har = [h_tau | ro_{tau-1}] via uncached direct-to-LDS 1KB loads
      {
        if (wv == 0) {
          const float* hb = ws + HTA_OFF + (size_t)(tau + 1) * 16384 + (size_t)n * 512 + (size_t)ln * 4;
          ASYNC_LD16(hb,       &sm.d.har[0]);
          ASYNC_LD16(hb + 256, &sm.d.har[256]);
        } else if (wv == 1) {
          const float* rb = ws + ROB_OFF + (size_t)tau * 8192 + (size_t)n * 256 + (size_t)ln * 4;
          ASYNC_LD16(rb, &sm.d.har[512]);
        }
        if (tid < 64) sm.d.v[tid] = vreg;
        else if (tid < 128) sm.d.kr[tid - 64] = kreg;
      }
      __syncthreads();   // drains async vmcnt + lgkm
      // action(10)+query(64) matvec from REGISTER weights: 222 threads = 37 pairs x 6 K-subs
      if (tid < 222) {
        const float* hc = sm.d.har + s6 * 128;
        float acc0 = 0.f, acc1 = 0.f;
#pragma unroll
        for (int r = 0; r < 128; ++r) {
          float h = hc[r];
          acc0 = fmaf(wreg[r].x, h, acc0);
          acc1 = fmaf(wreg[r].y, h, acc1);
        }
        sm.d.scrq[(s6 * 37 + p37) * 2 + 0] = acc0;
        sm.d.scrq[(s6 * 37 + p37) * 2 + 1] = acc1;
      }
      __syncthreads();
      // reduce 6 K-subs + bias -> act / q   (output o = tid = 2j+half)
      if (tid < 74) {
        int j = tid >> 1, half = tid & 1;
        float sacc = 0.f;
#pragma unroll
        for (int sub = 0; sub < 6; ++sub) sacc += sm.d.scrq[(sub * 37 + j) * 2 + half];
        float val = sacc + ws[BAQ_OFF + tpp * 74 + tid];
        if (tid < 10) sm.d.act[tid] = val; else sm.d.q[tid - 10] = val;
      }
      __syncthreads();
      float rd0, rd1, rd2, rd3, wd0, wd1, wd2, wd3, rw0, rw1;
      {
        float a0 = sm.d.act[0], a1 = sm.d.act[1], a2 = sm.d.act[2], a3 = sm.d.act[3];
        float mx = fmaxf(fmaxf(a0, a1), fmaxf(a2, a3));
        float e0 = expf(a0 - mx), e1 = expf(a1 - mx), e2 = expf(a2 - mx), e3 = expf(a3 - mx);
        float inv = 1.f / (e0 + e1 + e2 + e3);
        rd0 = e0 * inv; rd1 = e1 * inv; rd2 = e2 * inv; rd3 = e3 * inv;
        a0 = sm.d.act[4]; a1 = sm.d.act[5]; a2 = sm.d.act[6]; a3 = sm.d.act[7];
        mx = fmaxf(fmaxf(a0, a1), fmaxf(a2, a3));
        e0 = expf(a0 - mx); e1 = expf(a1 - mx); e2 = expf(a2 - mx); e3 = expf(a3 - mx);
        inv = 1.f / (e0 + e1 + e2 + e3);
        wd0 = e0 * inv; wd1 = e1 * inv; wd2 = e2 * inv; wd3 = e3 * inv;
        rw0 = 1.f / (1.f + expf(-sm.d.act[8]));
        rw1 = 1.f / (1.f + expf(-sm.d.act[9]));
      }
      const int c = tid & 63, ls = tid >> 6;
      {
        float pv = 0.f, pk = 0.f;
#pragma unroll
        for (int i = 0; i < 8; ++i) {
          int l = ls * 8 + i;
          float wp = sm.d.wpos[l];
          pv = fmaf(sm.d.tape[l][c], wp, pv);
          pk = fmaf(sm.d.tkey[l][c], wp, pk);
        }
        sm.d.scrA[tid] = pv; sm.d.scrB[tid] = pk;
      }
      __syncthreads();
      if (tid < 64) {
        float ov = sm.d.scrA[tid] + sm.d.scrA[tid + 64] + sm.d.scrA[tid + 128] + sm.d.scrA[tid + 192];
        float ok = sm.d.scrB[tid] + sm.d.scrB[tid + 64] + sm.d.scrB[tid + 128] + sm.d.scrB[tid + 192];
        sm.d.dv[tid] = (sm.d.v[tid] - ov) * rw1;
        sm.d.dk[tid] = (sm.d.kr[tid] - ok) * rw1;
      }
      __syncthreads();
      {
        float pr = 0.f;
        float dvc = sm.d.dv[c], dkc = sm.d.dk[c];
#pragma unroll
        for (int i = 0; i < 8; ++i) {
          int l = ls * 8 + i;
          float wp = sm.d.wpos[l];
          float tv = sm.d.tape[l][c] + wp * dvc;
          sm.d.tape[l][c] = tv;
          sm.d.tkey[l][c] += wp * dkc;
          pr = fmaf(tv, sm.d.rpos[l], pr);
        }
        sm.d.scrA[tid] = pr;
      }
      __syncthreads();
      float rov = 0.f;
      if (tid < 64)
        rov = (sm.d.scrA[tid] + sm.d.scrA[tid + 64] + sm.d.scrA[tid + 128] + sm.d.scrA[tid + 192]) * rw0;
      {
        int l2 = tid & 31, cs2 = tid >> 5;
        float pj = 0.f;
#pragma unroll
        for (int i = 0; i < 8; ++i) {
          int cc = cs2 * 8 + i;
          pj = fmaf(sm.d.tkey[l2][cc], sm.d.q[cc], pj);
        }
        sm.d.scrB[tid] = pj;
      }
      __syncthreads();
      float jp = 0.f;
      if (tid < 32) {
#pragma unroll
        for (int cs3 = 0; cs3 < 8; ++cs3) jp += sm.d.scrB[cs3 * 32 + tid];
      }
      if (tid < 64) {
        float v2 = (tid < 32) ? jp : 0.f;
        float ss = v2 * v2;
#pragma unroll
        for (int off = 32; off > 0; off >>= 1) ss += __shfl_down(ss, off, 64);
        if (tid == 0) sm.d.norm = fmaxf(sqrtf(ss), 1e-12f);
      }
      __syncthreads();
      if (tid < 32) {
        float jn = jp / sm.d.norm;
        float prv = sm.d.rpos[(tid + 1) & 31];
        float nxt = sm.d.rpos[(tid + 31) & 31];
        float rp = sm.d.rpos[tid], wp = sm.d.wpos[tid];
        sm.d.wpos[tid] = prv * wd0 + wp * wd1 + nxt * wd2 + jn * wd3;
        sm.d.rpos[tid] = prv * rd0 + rp * rd1 + nxt * rd2 + jn * rd3;
      }
      if (tid < 64)
        coh_st(ws + ROB_OFF + (size_t)(tau + 1) * 8192 + n * 256 + tpp * 64 + tid, rov);
      __syncthreads();   // rpos/wpos LDS + ROB stores drained before flag
      if (tid == 0) coh_stu_rel(tflg + g * 16, (unsigned)(tau + 1));
    }
    // final tape write-out
    for (int i = tid; i < 2048; i += 256) {
      int l = i >> 6, cc = i & 63;
      out[4194304 + (size_t)(l * 32 + n) * 256 + tpp * 64 + cc] = sm.d.tape[l][cc];
    }
  }
}

// out[s][n][d] = sum_m ROB[s+1][n][m] * Wo[m][d] + bo[d]; LDS-transposed ro tile
__global__ __launch_bounds__(256) void k_out_gemm(const float* __restrict__ rob, const float* __restrict__ Wo,
                                                  const float* __restrict__ bo, float* __restrict__ out) {
  __shared__ __align__(16) float ro[256 * 32];   // [m][n], XOR-swizzled float4 chunks over n
  int s = blockIdx.x >> 1, dh = blockIdx.x & 1;
  int d = dh * 256 + threadIdx.x;
  const int tid = threadIdx.x;
  const float* src = rob + (size_t)(s + 1) * 8192;   // slot s+1 = read_outs step s
  for (int w = 0; w < 32; ++w) {
    int idx = tid + w * 256;                 // idx = n*256 + m
    int n = idx >> 8, m = idx & 255;
    float v = src[idx];
    ro[m * 32 + ((((n >> 2) ^ (m & 7)) << 2) | (n & 3))] = v;
  }
  __syncthreads();
  float acc[32];
#pragma unroll
  for (int n = 0; n < 32; ++n) acc[n] = 0.f;
  for (int m = 0; m < 256; ++m) {
    float w = Wo[m * 512 + d];
    const float4* rc = (const float4*)(ro + m * 32);
#pragma unroll
    for (int j = 0; j < 8; ++j) {
      float4 r4 = rc[j ^ (m & 7)];
      acc[4 * j + 0] = fmaf(r4.x, w, acc[4 * j + 0]);
      acc[4 * j + 1] = fmaf(r4.y, w, acc[4 * j + 1]);
      acc[4 * j + 2] = fmaf(r4.z, w, acc[4 * j + 2]);
      acc[4 * j + 3] = fmaf(r4.w, w, acc[4 * j + 3]);
    }
  }
  float bd = bo[d];
#pragma unroll
  for (int n = 0; n < 32; ++n) out[(size_t)(s * 32 + n) * 512 + d] = acc[n] + bd;
}

extern "C" void kernel_launch(void* const* d_in, const int* in_sizes, int n_in,
                              void* d_out, int out_size, void* d_ws, size_t ws_size,
                              hipStream_t stream) {
  const float* inp = (const float*)d_in[0];
  const float* Wih = (const float*)d_in[1];
  const float* Whh = (const float*)d_in[2];
  const float* bih = (const float*)d_in[3];
  const float* bhh = (const float*)d_in[4];
  const float* Wa  = (const float*)d_in[5];
  const float* ba  = (const float*)d_in[6];
  const float* Wv  = (const float*)d_in[7];
  const float* bv  = (const float*)d_in[8];
  const float* Wk  = (const float*)d_in[9];
  const float* bk  = (const float*)d_in[10];
  const float* Wq  = (const float*)d_in[11];
  const float* bq  = (const float*)d_in[12];
  const float* Wo  = (const float*)d_in[13];
  const float* bo  = (const float*)d_in[14];
  float* ws = (float*)d_ws;
  float* out = (float*)d_out;

  hipMemsetAsync(ws + HTA_OFF, 0, 16384 * sizeof(float), stream);    // h_{-1} slot
  hipMemsetAsync(ws + ROB_OFF, 0, 8192 * sizeof(float), stream);     // ro_{-1} slot
  hipMemsetAsync(ws + LFLG_OFF, 0, 4096 * sizeof(unsigned), stream); // LFLG + TFLG
  k_prep_waq<<<dim3(296, 3), 256, 0, stream>>>(Wa, ba, Wq, bq, ws);
  k_pre<<<2560, 256, 0, stream>>>(inp, Wih, bih, bhh, Wv, bv, Wk, bk, ws);
  k_knorm<<<8192, 256, 0, stream>>>(ws);

  // Plain launch — flag-spin protocol only; all 256 blocks co-resident.
  nam_coop<<<dim3(256), dim3(256), 0, stream>>>(Whh, ws, out);

  k_out_gemm<<<512, 256, 0, stream>>>(ws + ROB_OFF, Wo, bo, out);
}

// Round 10
// 3003.476 us; speedup vs baseline: 3.4533x; 1.0882x over previous
//
#include <hip/hip_runtime.h>

#define S_LEN 256
// ws float offsets — TOTAL 27,519,488 floats = 110.08 MB (unchanged)
#define GI_OFF     0u           // [256][2048][32]  x@Wih + bih + bhh, [s][col][n]
#define VAL_OFF    16777216u    // [256][32][256]   x@Wv + bv
#define KEY_OFF    18874368u    // [256][32][256]   unitnorm(x@Wk + bk)
#define HTA_OFF    20971520u    // [257][32][512]   h history, BATCH-MAJOR: slot t+1 = h_t, [n][d]
#define ROB_OFF    25182208u    // [257][32][256]   read_out full history, slot t+1 = ro_t
#define WAQT_OFF   27287552u    // [768][296] K-MAJOR fused action+query weights fp32
#define BAQ_OFF    27514880u    // [296] biases (padded 512)
#define LFLG_OFF   27515392u    // 128 LSTM flags (pod*32+c), stride 16 u32
#define TFLG_OFF   27517440u    // 128 tape flags, stride 16 u32
#define WS_TOTAL   27519488u

// dynamic-LDS layout (tape branch); LSTM branch reuses first 16 KB as hs[4096]
#define L_WLDS  0u        // float [28416] = 113,664 B : K-rows 0..383 x 74 outs (fp32)
#define L_TAPE  113664u   // float [32][64]
#define L_TKEY  121856u   // float [32][64]
#define L_HAR   130048u   // float [768]
#define L_SCRA  133120u   // float [256]
#define L_SCRB  134144u   // float [256]
#define L_SCRQ  135168u   // float [448]  matvec partials (sub*37+j)*2+half
#define L_RPOS  136960u   // float [32]
#define L_WPOS  137088u   // float [32]
#define L_ACT   137216u   // float [16]
#define L_Q     137280u   // float [64]
#define L_V     137536u   // float [64]
#define L_KR    137792u   // float [64]
#define L_DV    138048u   // float [64]
#define L_DK    138304u   // float [64]
#define L_NORM  138560u   // float [1]
#define DYN_LDS 138752u

typedef __attribute__((address_space(1))) const void glb_cv;
typedef __attribute__((address_space(3))) void lds_v;

// ---- agent-scope helpers ----
__device__ __forceinline__ void coh_st(float* p, float v) {
  __hip_atomic_store(p, v, __ATOMIC_RELAXED, __HIP_MEMORY_SCOPE_AGENT);
}
__device__ __forceinline__ unsigned coh_ldu(const unsigned* p) {
  return __hip_atomic_load(p, __ATOMIC_RELAXED, __HIP_MEMORY_SCOPE_AGENT);
}
// RELEASE flag store: full agent-scope release sequence (R0 fix — keep).
__device__ __forceinline__ void coh_stu_rel(unsigned* p, unsigned v) {
  __hip_atomic_store(p, v, __ATOMIC_RELEASE, __HIP_MEMORY_SCOPE_AGENT);
}
// Uncached (SC0|SC1 = LLC-coherent) direct-to-LDS 16B/lane load (R3, proven).
#define ASYNC_LD16(gsrc, ldst) \
  __builtin_amdgcn_global_load_lds((glb_cv*)(gsrc), (lds_v*)(ldst), 16, 0, 17)

// Wait until 32 pod flags >= tgt (wave 0 polls, 1 flag/lane, lanes>=32 duplicate)
__device__ __forceinline__ void wait_pod(const unsigned* f, int base, int tid, unsigned tgt) {
  if (tid < 64) {
    const unsigned* fp = f + (size_t)(base + (tid & 31)) * 16;
    while (true) {
      unsigned a = coh_ldu(fp);
      if (__all(a >= tgt)) break;
      __builtin_amdgcn_s_sleep(1);
    }
    asm volatile("" ::: "memory");   // nothing hoists above the spin
  }
}

// ---- parallel pre-pass: gi = x@Wih + bih + bhh ; values = x@Wv+bv ; keys_raw = x@Wk+bk ----
__global__ __launch_bounds__(256) void k_pre(const float* __restrict__ inp,
    const float* __restrict__ Wih, const float* __restrict__ bih, const float* __restrict__ bhh,
    const float* __restrict__ Wv, const float* __restrict__ bv,
    const float* __restrict__ Wk, const float* __restrict__ bk, float* __restrict__ ws)
{
  __shared__ __align__(16) float xs[256 * 32];
  const int s = blockIdx.x / 10, tile = blockIdx.x % 10;
  const int tid = threadIdx.x;
  const float* W; int C, c;
  if (tile < 8)       { W = Wih; C = 2048; c = tile * 256 + tid; }
  else if (tile == 8) { W = Wv;  C = 256;  c = tid; }
  else                { W = Wk;  C = 256;  c = tid; }

  float acc[32];
#pragma unroll
  for (int n = 0; n < 32; ++n) acc[n] = 0.f;

  for (int p = 0; p < 2; ++p) {
    __syncthreads();
    for (int w = 0; w < 32; ++w) {
      int i = tid + w * 256;
      int k = i & 255, n = i >> 8;
      float v = inp[s * 16384 + n * 512 + p * 256 + k];
      int pos = ((((n >> 2) + (k & 7)) & 7) << 2) | (n & 3);
      xs[k * 32 + pos] = v;
    }
    __syncthreads();
    const float* Wp = W + (size_t)(p * 256) * C + c;
#pragma unroll 8
    for (int kk = 0; kk < 256; ++kk) {
      float wv = Wp[(size_t)kk * C];
      const float4* row = (const float4*)(xs + kk * 32);
#pragma unroll
      for (int j = 0; j < 8; ++j) {
        float4 a = row[(j + (kk & 7)) & 7];
        acc[4 * j + 0] = fmaf(a.x, wv, acc[4 * j + 0]);
        acc[4 * j + 1] = fmaf(a.y, wv, acc[4 * j + 1]);
        acc[4 * j + 2] = fmaf(a.z, wv, acc[4 * j + 2]);
        acc[4 * j + 3] = fmaf(a.w, wv, acc[4 * j + 3]);
      }
    }
  }

  if (tile < 8) {
    float bb = bih[c] + bhh[c];
    float4* dst = (float4*)(ws + GI_OFF + (size_t)s * 65536 + (size_t)c * 32);
#pragma unroll
    for (int j = 0; j < 8; ++j)
      dst[j] = make_float4(acc[4 * j] + bb, acc[4 * j + 1] + bb, acc[4 * j + 2] + bb, acc[4 * j + 3] + bb);
  } else {
    unsigned base = (tile == 8) ? VAL_OFF : KEY_OFF;
    float bb = (tile == 8) ? bv[c] : bk[c];
#pragma unroll
    for (int n = 0; n < 32; ++n)
      ws[base + (size_t)s * 8192 + n * 256 + c] = acc[n] + bb;
  }
}

__global__ __launch_bounds__(256) void k_knorm(float* __restrict__ ws) {
  int b = blockIdx.x;
  int m = threadIdx.x;
  float* p = ws + KEY_OFF + (size_t)b * 256;
  float x = p[m];
  float ss = x * x;
#pragma unroll
  for (int off = 32; off > 0; off >>= 1) ss += __shfl_xor(ss, off, 64);
  p[m] = x / fmaxf(sqrtf(ss), 1e-12f);
}

// Build K-MAJOR fused action+query weight table WAQT_T[768][296] (+ biases BAQ[296]).
__global__ __launch_bounds__(256) void k_prep_waq(const float* __restrict__ Wa, const float* __restrict__ ba,
                                                  const float* __restrict__ Wq, const float* __restrict__ bq,
                                                  float* __restrict__ ws) {
  int o = blockIdx.x;                       // global output 0..295 (tp*74 + j)
  int k = blockIdx.y * 256 + threadIdx.x;   // 0..767
  int tp = o / 74, j = o - tp * 74;
  float v = (j < 10) ? Wa[k * 40 + tp * 10 + j] : Wq[k * 256 + tp * 64 + (j - 10)];
  ws[WAQT_OFF + (size_t)k * 296 + o] = v;
  if (k == 0) ws[BAQ_OFF + o] = (j < 10) ? ba[tp * 10 + j] : bq[tp * 64 + (j - 10)];
}

// Plain (non-cooperative) launch: flag-spin protocol only; 256 blocks at 1/CU, all
// co-resident (138.75 KB dynamic LDS). R5 topology: 128 LSTM (4 pods x 32) + 128
// tape (n,tp). NEW: tape weights fp32, FULLY resident — K-rows 0..383 in LDS
// (111 KB, staged once) + K-rows 384..767 in registers (64 float2/thread = 128
// VGPR, fits the 256-VGPR addressable file; R9's 256-VGPR attempt spilled).
// Zero per-step weight traffic.
__global__ __launch_bounds__(256, 1) void nam_coop(
    const float* __restrict__ Whh, float* __restrict__ ws, float* __restrict__ out)
{
  extern __shared__ __align__(16) char smraw[];
  const int blk = blockIdx.x, tid = threadIdx.x;
  unsigned* lflg = (unsigned*)(ws + LFLG_OFF);
  unsigned* tflg = (unsigned*)(ws + TFLG_OFF);

  if (blk < 128) {
    // ============ LSTM block: pod = blk>>5 (8 batches), 16 dims x 4 gates (R3-R9, proven) ============
    float* hs = (float*)smraw;   // [4096] = pod's 8 h-rows
    const int pod = blk >> 5, c = blk & 31;
    const int ks = tid & 15, cq = tid >> 4;
    const int dg = c * 16 + cq;
    float wG0[32], wG1[32], wG2[32], wG3[32];
#pragma unroll
    for (int j = 0; j < 32; ++j) {
      const float* wr = Whh + (size_t)(j * 16 + ks) * 2048 + dg;
      wG0[j] = wr[0]; wG1[j] = wr[512]; wG2[j] = wr[1024]; wG3[j] = wr[1536];
    }
    const bool fin = (ks == 0);
    float creg[8];
#pragma unroll
    for (int e = 0; e < 8; ++e) creg[e] = 0.f;

    const int wv = tid >> 6, ln = tid & 63;

    for (int t = 0; t < S_LEN; ++t) {
      float gi[32];
      if (fin) {
        const float* gb = ws + GI_OFF + (size_t)t * 65536 + (size_t)dg * 32 + pod * 8;
#pragma unroll
        for (int g = 0; g < 4; ++g) {
          float4 lo = *(const float4*)(gb + (size_t)g * 16384);
          float4 hi = *(const float4*)(gb + (size_t)g * 16384 + 4);
          gi[g * 8 + 0] = lo.x; gi[g * 8 + 1] = lo.y; gi[g * 8 + 2] = lo.z; gi[g * 8 + 3] = lo.w;
          gi[g * 8 + 4] = hi.x; gi[g * 8 + 5] = hi.y; gi[g * 8 + 6] = hi.z; gi[g * 8 + 7] = hi.w;
        }
      }
      if (t > 0) wait_pod(lflg, pod * 32, tid, (unsigned)t);
      __syncthreads();
      {
        const float* hsrc = ws + HTA_OFF + (size_t)t * 16384 + (size_t)pod * 4096
                          + (size_t)wv * 1024 + (size_t)ln * 4;
#pragma unroll
        for (int i = 0; i < 4; ++i)
          ASYNC_LD16(hsrc + i * 256, &hs[wv * 1024 + i * 256]);
      }
      __syncthreads();   // drains vmcnt (async LDS loads)
      float a0[8], a1[8], a2[8], a3[8];
#pragma unroll
      for (int e = 0; e < 8; ++e) { a0[e] = 0.f; a1[e] = 0.f; a2[e] = 0.f; a3[e] = 0.f; }
#pragma unroll
      for (int j = 0; j < 32; ++j) {
        const int kk = j * 16 + ks;
        float w0 = wG0[j], w1 = wG1[j], w2 = wG2[j], w3 = wG3[j];
#pragma unroll
        for (int e = 0; e < 8; ++e) {
          float hv = hs[e * 512 + kk];
          a0[e] = fmaf(hv, w0, a0[e]);
          a1[e] = fmaf(hv, w1, a1[e]);
          a2[e] = fmaf(hv, w2, a2[e]);
          a3[e] = fmaf(hv, w3, a3[e]);
        }
      }
#pragma unroll
      for (int e = 0; e < 8; ++e) {
        float v0 = a0[e], v1 = a1[e], v2 = a2[e], v3 = a3[e];
        v0 += __shfl_down(v0, 8, 16); v1 += __shfl_down(v1, 8, 16);
        v2 += __shfl_down(v2, 8, 16); v3 += __shfl_down(v3, 8, 16);
        v0 += __shfl_down(v0, 4, 16); v1 += __shfl_down(v1, 4, 16);
        v2 += __shfl_down(v2, 4, 16); v3 += __shfl_down(v3, 4, 16);
        v0 += __shfl_down(v0, 2, 16); v1 += __shfl_down(v1, 2, 16);
        v2 += __shfl_down(v2, 2, 16); v3 += __shfl_down(v3, 2, 16);
        v0 += __shfl_down(v0, 1, 16); v1 += __shfl_down(v1, 1, 16);
        v2 += __shfl_down(v2, 1, 16); v3 += __shfl_down(v3, 1, 16);
        a0[e] = v0; a1[e] = v1; a2[e] = v2; a3[e] = v3;
      }
      if (fin) {
        float* hdst = ws + HTA_OFF + (size_t)(t + 1) * 16384 + (size_t)pod * 4096 + dg;
#pragma unroll
        for (int e = 0; e < 8; ++e) {
          float gvi = a0[e] + gi[e];
          float gvf = a1[e] + gi[8 + e];
          float gvg = a2[e] + gi[16 + e];
          float gvo = a3[e] + gi[24 + e];
          float si = 1.f / (1.f + expf(-gvi));
          float sf = 1.f / (1.f + expf(-gvf));
          float so = 1.f / (1.f + expf(-gvo));
          float cn = sf * creg[e] + si * tanhf(gvg);
          float hn = so * tanhf(cn);
          creg[e] = cn;
          coh_st(hdst + (size_t)e * 512, hn);
        }
      }
      __syncthreads();   // h stores vmcnt-drained before flag
      if (tid == 0) coh_stu_rel(lflg + blk * 16, (unsigned)(t + 1));
    }
  } else {
    // ============ tape block: one (n, tp) group (R5 structure, LDS+REG fp32 weights) ============
    float* wldsf = (float*)(smraw + L_WLDS);     // [384][74] K-rows 0..383
    float* tape = (float*)(smraw + L_TAPE);
    float* tkey = (float*)(smraw + L_TKEY);
    float* har  = (float*)(smraw + L_HAR);
    float* scrA = (float*)(smraw + L_SCRA);
    float* scrB = (float*)(smraw + L_SCRB);
    float* scrq = (float*)(smraw + L_SCRQ);
    float* rpos = (float*)(smraw + L_RPOS);
    float* wpos = (float*)(smraw + L_WPOS);
    float* actb = (float*)(smraw + L_ACT);
    float* qv   = (float*)(smraw + L_Q);
    float* vvb  = (float*)(smraw + L_V);
    float* krs  = (float*)(smraw + L_KR);
    float* dvs  = (float*)(smraw + L_DV);
    float* dks  = (float*)(smraw + L_DK);
    float* normp= (float*)(smraw + L_NORM);

    const int g = blk - 128, n = g >> 2, tpp = g & 3;
    const int lpodbase = (n >> 3) * 32;
    const int p37 = tid % 37, s6 = tid / 37;     // matvec task: 222 active threads

    // prologue 1: stage K-rows 0..383 of this tape's weight slice into LDS (fp32, once)
    {
      const float* wsrc = ws + WAQT_OFF;
      for (int i = tid; i < 28416; i += 256) {
        int row = i / 74, j = i - row * 74;
        wldsf[i] = wsrc[(size_t)row * 296 + tpp * 74 + j];
      }
    }
    // prologue 2: K-rows 384..767 into registers (64 float2 = 128 VGPR, fits)
    float2 wreg[64];
    if (tid < 222) {
      const float* wb = ws + WAQT_OFF + (size_t)(384 + s6 * 64) * 296 + tpp * 74 + 2 * p37;
#pragma unroll
      for (int r = 0; r < 64; ++r)
        wreg[r] = *(const float2*)(wb + (size_t)r * 296);
    }
    for (int i = tid; i < 2048; i += 256) { tape[i] = 0.f; tkey[i] = 0.f; }
    if (tid < 32) { rpos[tid] = (tid == 0) ? 1.f : 0.f; wpos[tid] = (tid == 0) ? 1.f : 0.f; }
    __syncthreads();

    const int wv = tid >> 6, ln = tid & 63;

    for (int tau = 0; tau < S_LEN; ++tau) {
      // flag-independent prefetch (plain cached)
      float vreg = 0.f, kreg = 0.f;
      if (tid < 64)        vreg = ws[VAL_OFF + (size_t)tau * 8192 + n * 256 + tpp * 64 + tid];
      else if (tid < 128)  kreg = ws[KEY_OFF + (size_t)tau * 8192 + n * 256 + tpp * 64 + (tid - 64)];
      // wait: h_tau ready (own pod's 32 flags), sibling ro_{tau-1} ready (4 tape flags)
      wait_pod(lflg, lpodbase, tid, (unsigned)(tau + 1));
      if (tid < 64 && tau > 0) {
        unsigned tgt2 = (unsigned)tau;
        while (true) {
          unsigned a = (tid < 4) ? coh_ldu(tflg + (n * 4 + tid) * 16) : tgt2;
          if (__all(a >= tgt2)) break;
          __builtin_amdgcn_s_sleep(1);
        }
        asm volatile("" ::: "memory");
      }
      __syncthreads();
      // stage har = [h_tau | ro_{tau-1}] via uncached direct-to-LDS 1KB loads
      {
        if (wv == 0) {
          const float* hb = ws + HTA_OFF + (size_t)(tau + 1) * 16384 + (size_t)n * 512 + (size_t)ln * 4;
          ASYNC_LD16(hb,       &har[0]);
          ASYNC_LD16(hb + 256, &har[256]);
        } else if (wv == 1) {
          const float* rb = ws + ROB_OFF + (size_t)tau * 8192 + (size_t)n * 256 + (size_t)ln * 4;
          ASYNC_LD16(rb, &har[512]);
        }
        if (tid < 64) vvb[tid] = vreg;
        else if (tid < 128) krs[tid - 64] = kreg;
      }
      __syncthreads();   // drains async vmcnt + lgkm
      // action(10)+query(64) matvec, ZERO global traffic: 64 LDS rows + 64 reg rows per thread
      if (tid < 222) {
        float acc0 = 0.f, acc1 = 0.f;
        const float2* w2 = (const float2*)wldsf;
        const float* hL = har + s6 * 64;
#pragma unroll
        for (int r = 0; r < 64; ++r) {
          float2 wvp = w2[(s6 * 64 + r) * 37 + p37];
          float h = hL[r];
          acc0 = fmaf(wvp.x, h, acc0);
          acc1 = fmaf(wvp.y, h, acc1);
        }
        const float* hR = har + 384 + s6 * 64;
#pragma unroll
        for (int r = 0; r < 64; ++r) {
          float h = hR[r];
          acc0 = fmaf(wreg[r].x, h, acc0);
          acc1 = fmaf(wreg[r].y, h, acc1);
        }
        scrq[(s6 * 37 + p37) * 2 + 0] = acc0;
        scrq[(s6 * 37 + p37) * 2 + 1] = acc1;
      }
      __syncthreads();
      // reduce 6 K-subs + bias -> act / q   (output o = tid = 2j+half)
      if (tid < 74) {
        int j = tid >> 1, half = tid & 1;
        float sacc = 0.f;
#pragma unroll
        for (int sub = 0; sub < 6; ++sub) sacc += scrq[(sub * 37 + j) * 2 + half];
        float val = sacc + ws[BAQ_OFF + tpp * 74 + tid];
        if (tid < 10) actb[tid] = val; else qv[tid - 10] = val;
      }
      __syncthreads();
      float rd0, rd1, rd2, rd3, wd0, wd1, wd2, wd3, rw0, rw1;
      {
        float a0 = actb[0], a1 = actb[1], a2 = actb[2], a3 = actb[3];
        float mx = fmaxf(fmaxf(a0, a1), fmaxf(a2, a3));
        float e0 = expf(a0 - mx), e1 = expf(a1 - mx), e2 = expf(a2 - mx), e3 = expf(a3 - mx);
        float inv = 1.f / (e0 + e1 + e2 + e3);
        rd0 = e0 * inv; rd1 = e1 * inv; rd2 = e2 * inv; rd3 = e3 * inv;
        a0 = actb[4]; a1 = actb[5]; a2 = actb[6]; a3 = actb[7];
        mx = fmaxf(fmaxf(a0, a1), fmaxf(a2, a3));
        e0 = expf(a0 - mx); e1 = expf(a1 - mx); e2 = expf(a2 - mx); e3 = expf(a3 - mx);
        inv = 1.f / (e0 + e1 + e2 + e3);
        wd0 = e0 * inv; wd1 = e1 * inv; wd2 = e2 * inv; wd3 = e3 * inv;
        rw0 = 1.f / (1.f + expf(-actb[8]));
        rw1 = 1.f / (1.f + expf(-actb[9]));
      }
      const int c = tid & 63, ls = tid >> 6;
      {
        float pv = 0.f, pk = 0.f;
#pragma unroll
        for (int i = 0; i < 8; ++i) {
          int l = ls * 8 + i;
          float wp = wpos[l];
          pv = fmaf(tape[l * 64 + c], wp, pv);
          pk = fmaf(tkey[l * 64 + c], wp, pk);
        }
        scrA[tid] = pv; scrB[tid] = pk;
      }
      __syncthreads();
      if (tid < 64) {
        float ov = scrA[tid] + scrA[tid + 64] + scrA[tid + 128] + scrA[tid + 192];
        float ok = scrB[tid] + scrB[tid + 64] + scrB[tid + 128] + scrB[tid + 192];
        dvs[tid] = (vvb[tid] - ov) * rw1;
        dks[tid] = (krs[tid] - ok) * rw1;
      }
      __syncthreads();
      {
        float pr = 0.f;
        float dvc = dvs[c], dkc = dks[c];
#pragma unroll
        for (int i = 0; i < 8; ++i) {
          int l = ls * 8 + i;
          float wp = wpos[l];
          float tv = tape[l * 64 + c] + wp * dvc;
          tape[l * 64 + c] = tv;
          tkey[l * 64 + c] += wp * dkc;
          pr = fmaf(tv, rpos[l], pr);
        }
        scrA[tid] = pr;
      }
      __syncthreads();
      float rov = 0.f;
      if (tid < 64)
        rov = (scrA[tid] + scrA[tid + 64] + scrA[tid + 128] + scrA[tid + 192]) * rw0;
      {
        int l2 = tid & 31, cs2 = tid >> 5;
        float pj = 0.f;
#pragma unroll
        for (int i = 0; i < 8; ++i) {
          int cc = cs2 * 8 + i;
          pj = fmaf(tkey[l2 * 64 + cc], qv[cc], pj);
        }
        scrB[tid] = pj;
      }
      __syncthreads();
      float jp = 0.f;
      if (tid < 32) {
#pragma unroll
        for (int cs3 = 0; cs3 < 8; ++cs3) jp += scrB[cs3 * 32 + tid];
      }
      if (tid < 64) {
        float v2 = (tid < 32) ? jp : 0.f;
        float ss = v2 * v2;
#pragma unroll
        for (int off = 32; off > 0; off >>= 1) ss += __shfl_down(ss, off, 64);
        if (tid == 0) normp[0] = fmaxf(sqrtf(ss), 1e-12f);
      }
      __syncthreads();
      if (tid < 32) {
        float jn = jp / normp[0];
        float prv = rpos[(tid + 1) & 31];
        float nxt = rpos[(tid + 31) & 31];
        float rp = rpos[tid], wp = wpos[tid];
        wpos[tid] = prv * wd0 + wp * wd1 + nxt * wd2 + jn * wd3;
        rpos[tid] = prv * rd0 + rp * rd1 + nxt * rd2 + jn * rd3;
      }
      if (tid < 64)
        coh_st(ws + ROB_OFF + (size_t)(tau + 1) * 8192 + n * 256 + tpp * 64 + tid, rov);
      __syncthreads();   // rpos/wpos LDS + ROB stores drained before flag
      if (tid == 0) coh_stu_rel(tflg + g * 16, (unsigned)(tau + 1));
    }
    // final tape write-out
    for (int i = tid; i < 2048; i += 256) {
      int l = i >> 6, cc = i & 63;
      out[4194304 + (size_t)(l * 32 + n) * 256 + tpp * 64 + cc] = tape[l * 64 + cc];
    }
  }
}

// out[s][n][d] = sum_m ROB[s+1][n][m] * Wo[m][d] + bo[d]; LDS-transposed ro tile
__global__ __launch_bounds__(256) void k_out_gemm(const float* __restrict__ rob, const float* __restrict__ Wo,
                                                  const float* __restrict__ bo, float* __restrict__ out) {
  __shared__ __align__(16) float ro[256 * 32];   // [m][n], XOR-swizzled float4 chunks over n
  int s = blockIdx.x >> 1, dh = blockIdx.x & 1;
  int d = dh * 256 + threadIdx.x;
  const int tid = threadIdx.x;
  const float* src = rob + (size_t)(s + 1) * 8192;   // slot s+1 = read_outs step s
  for (int w = 0; w < 32; ++w) {
    int idx = tid + w * 256;                 // idx = n*256 + m
    int n = idx >> 8, m = idx & 255;
    float v = src[idx];
    ro[m * 32 + ((((n >> 2) ^ (m & 7)) << 2) | (n & 3))] = v;
  }
  __syncthreads();
  float acc[32];
#pragma unroll
  for (int n = 0; n < 32; ++n) acc[n] = 0.f;
  for (int m = 0; m < 256; ++m) {
    float w = Wo[m * 512 + d];
    const float4* rc = (const float4*)(ro + m * 32);
#pragma unroll
    for (int j = 0; j < 8; ++j) {
      float4 r4 = rc[j ^ (m & 7)];
      acc[4 * j + 0] = fmaf(r4.x, w, acc[4 * j + 0]);
      acc[4 * j + 1] = fmaf(r4.y, w, acc[4 * j + 1]);
      acc[4 * j + 2] = fmaf(r4.z, w, acc[4 * j + 2]);
      acc[4 * j + 3] = fmaf(r4.w, w, acc[4 * j + 3]);
    }
  }
  float bd = bo[d];
#pragma unroll
  for (int n = 0; n < 32; ++n) out[(size_t)(s * 32 + n) * 512 + d] = acc[n] + bd;
}

extern "C" void kernel_launch(void* const* d_in, const int* in_sizes, int n_in,
                              void* d_out, int out_size, void* d_ws, size_t ws_size,
                              hipStream_t stream) {
  const float* inp = (const float*)d_in[0];
  const float* Wih = (const float*)d_in[1];
  const float* Whh = (const float*)d_in[2];
  const float* bih = (const float*)d_in[3];
  const float* bhh = (const float*)d_in[4];
  const float* Wa  = (const float*)d_in[5];
  const float* ba  = (const float*)d_in[6];
  const float* Wv  = (const float*)d_in[7];
  const float* bv  = (const float*)d_in[8];
  const float* Wk  = (const float*)d_in[9];
  const float* bk  = (const float*)d_in[10];
  const float* Wq  = (const float*)d_in[11];
  const float* bq  = (const float*)d_in[12];
  const float* Wo  = (const float*)d_in[13];
  const float* bo  = (const float*)d_in[14];
  float* ws = (float*)d_ws;
  float* out = (float*)d_out;

  // allow >64 KB dynamic LDS (host-side attribute; R8 validated this launches)
  static bool attr_set = false;
  if (!attr_set) {
    hipFuncSetAttribute((const void*)nam_coop,
                        hipFuncAttributeMaxDynamicSharedMemorySize, (int)DYN_LDS);
    attr_set = true;
  }

  hipMemsetAsync(ws + HTA_OFF, 0, 16384 * sizeof(float), stream);    // h_{-1} slot
  hipMemsetAsync(ws + ROB_OFF, 0, 8192 * sizeof(float), stream);     // ro_{-1} slot
  hipMemsetAsync(ws + LFLG_OFF, 0, 4096 * sizeof(unsigned), stream); // LFLG + TFLG
  k_prep_waq<<<dim3(296, 3), 256, 0, stream>>>(Wa, ba, Wq, bq, ws);
  k_pre<<<2560, 256, 0, stream>>>(inp, Wih, bih, bhh, Wv, bv, Wk, bk, ws);
  k_knorm<<<8192, 256, 0, stream>>>(ws);

  // Plain launch — flag-spin protocol only; 256 blocks at 1/CU, all co-resident.
  nam_coop<<<dim3(256), dim3(256), DYN_LDS, stream>>>(Whh, ws, out);

  k_out_gemm<<<512, 256, 0, stream>>>(ws + ROB_OFF, Wo, bo, out);
}

// Round 11
// 2968.496 us; speedup vs baseline: 3.4940x; 1.0118x over previous
//
#include <hip/hip_runtime.h>

#define S_LEN 256
// ws float offsets — TOTAL 27,519,488 floats = 110.08 MB (unchanged)
#define GI_OFF     0u           // [256][2048][32]  x@Wih + bih + bhh, [s][col][n]
#define VAL_OFF    16777216u    // [256][32][256]   x@Wv + bv
#define KEY_OFF    18874368u    // [256][32][256]   unitnorm(x@Wk + bk)
#define HTA_OFF    20971520u    // [257][32][512]   h history, BATCH-MAJOR: slot t+1 = h_t, [n][d]
#define ROB_OFF    25182208u    // [257][32][256]   read_out full history, slot t+1 = ro_t
#define WAQT_OFF   27287552u    // [768][296] K-MAJOR fused action+query weights fp32
#define BAQ_OFF    27514880u    // [296] biases (padded 512)
#define LFLG_OFF   27515392u    // 128 LSTM flags (pod*32+c), stride 16 u32
#define TFLG_OFF   27517440u    // 128 tape flags, stride 16 u32
#define WS_TOTAL   27519488u

// dynamic-LDS layout (tape branch); LSTM branch reuses first 16 KB as hs[4096]
#define L_WLDS  0u        // float [28416] = 113,664 B : K-rows 0..383 x 74 outs (fp32)
#define L_TAPE  113664u   // float [32][64]
#define L_TKEY  121856u   // float [32][64]
#define L_HAR   130048u   // float [768]
#define L_SCRA  133120u   // float [256]
#define L_SCRB  134144u   // float [256]
#define L_SCRQ  135168u   // float [448]  matvec partials (sub*37+j)*2+half
#define L_RPOS  136960u   // float [32]
#define L_WPOS  137088u   // float [32]
#define L_ACT   137216u   // float [16]
#define L_Q     137280u   // float [64]
#define L_V     137536u   // float [64]
#define L_KR    137792u   // float [64]
#define L_DV    138048u   // float [64]
#define L_DK    138304u   // float [64]
#define L_NORM  138560u   // float [1]
#define DYN_LDS 138752u

typedef __attribute__((address_space(1))) const void glb_cv;
typedef __attribute__((address_space(3))) void lds_v;

// ---- agent-scope helpers ----
__device__ __forceinline__ void coh_st(float* p, float v) {
  __hip_atomic_store(p, v, __ATOMIC_RELAXED, __HIP_MEMORY_SCOPE_AGENT);
}
__device__ __forceinline__ unsigned coh_ldu(const unsigned* p) {
  return __hip_atomic_load(p, __ATOMIC_RELAXED, __HIP_MEMORY_SCOPE_AGENT);
}
// RELEASE flag store: full agent-scope release sequence (R0 fix — keep).
__device__ __forceinline__ void coh_stu_rel(unsigned* p, unsigned v) {
  __hip_atomic_store(p, v, __ATOMIC_RELEASE, __HIP_MEMORY_SCOPE_AGENT);
}
// Uncached (SC0|SC1 = LLC-coherent) direct-to-LDS 16B/lane load (R3, proven).
#define ASYNC_LD16(gsrc, ldst) \
  __builtin_amdgcn_global_load_lds((glb_cv*)(gsrc), (lds_v*)(ldst), 16, 0, 17)

// Wait until 32 pod flags >= tgt (wave 0 polls, 1 flag/lane, lanes>=32 duplicate)
__device__ __forceinline__ void wait_pod(const unsigned* f, int base, int tid, unsigned tgt) {
  if (tid < 64) {
    const unsigned* fp = f + (size_t)(base + (tid & 31)) * 16;
    while (true) {
      unsigned a = coh_ldu(fp);
      if (__all(a >= tgt)) break;
      __builtin_amdgcn_s_sleep(1);
    }
    asm volatile("" ::: "memory");   // nothing hoists above the spin
  }
}

// ---- parallel pre-pass: gi = x@Wih + bih + bhh ; values = x@Wv+bv ; keys_raw = x@Wk+bk ----
__global__ __launch_bounds__(256) void k_pre(const float* __restrict__ inp,
    const float* __restrict__ Wih, const float* __restrict__ bih, const float* __restrict__ bhh,
    const float* __restrict__ Wv, const float* __restrict__ bv,
    const float* __restrict__ Wk, const float* __restrict__ bk, float* __restrict__ ws)
{
  __shared__ __align__(16) float xs[256 * 32];
  const int s = blockIdx.x / 10, tile = blockIdx.x % 10;
  const int tid = threadIdx.x;
  const float* W; int C, c;
  if (tile < 8)       { W = Wih; C = 2048; c = tile * 256 + tid; }
  else if (tile == 8) { W = Wv;  C = 256;  c = tid; }
  else                { W = Wk;  C = 256;  c = tid; }

  float acc[32];
#pragma unroll
  for (int n = 0; n < 32; ++n) acc[n] = 0.f;

  for (int p = 0; p < 2; ++p) {
    __syncthreads();
    for (int w = 0; w < 32; ++w) {
      int i = tid + w * 256;
      int k = i & 255, n = i >> 8;
      float v = inp[s * 16384 + n * 512 + p * 256 + k];
      int pos = ((((n >> 2) + (k & 7)) & 7) << 2) | (n & 3);
      xs[k * 32 + pos] = v;
    }
    __syncthreads();
    const float* Wp = W + (size_t)(p * 256) * C + c;
#pragma unroll 8
    for (int kk = 0; kk < 256; ++kk) {
      float wv = Wp[(size_t)kk * C];
      const float4* row = (const float4*)(xs + kk * 32);
#pragma unroll
      for (int j = 0; j < 8; ++j) {
        float4 a = row[(j + (kk & 7)) & 7];
        acc[4 * j + 0] = fmaf(a.x, wv, acc[4 * j + 0]);
        acc[4 * j + 1] = fmaf(a.y, wv, acc[4 * j + 1]);
        acc[4 * j + 2] = fmaf(a.z, wv, acc[4 * j + 2]);
        acc[4 * j + 3] = fmaf(a.w, wv, acc[4 * j + 3]);
      }
    }
  }

  if (tile < 8) {
    float bb = bih[c] + bhh[c];
    float4* dst = (float4*)(ws + GI_OFF + (size_t)s * 65536 + (size_t)c * 32);
#pragma unroll
    for (int j = 0; j < 8; ++j)
      dst[j] = make_float4(acc[4 * j] + bb, acc[4 * j + 1] + bb, acc[4 * j + 2] + bb, acc[4 * j + 3] + bb);
  } else {
    unsigned base = (tile == 8) ? VAL_OFF : KEY_OFF;
    float bb = (tile == 8) ? bv[c] : bk[c];
#pragma unroll
    for (int n = 0; n < 32; ++n)
      ws[base + (size_t)s * 8192 + n * 256 + c] = acc[n] + bb;
  }
}

__global__ __launch_bounds__(256) void k_knorm(float* __restrict__ ws) {
  int b = blockIdx.x;
  int m = threadIdx.x;
  float* p = ws + KEY_OFF + (size_t)b * 256;
  float x = p[m];
  float ss = x * x;
#pragma unroll
  for (int off = 32; off > 0; off >>= 1) ss += __shfl_xor(ss, off, 64);
  p[m] = x / fmaxf(sqrtf(ss), 1e-12f);
}

// Build K-MAJOR fused action+query weight table WAQT_T[768][296] (+ biases BAQ[296]).
__global__ __launch_bounds__(256) void k_prep_waq(const float* __restrict__ Wa, const float* __restrict__ ba,
                                                  const float* __restrict__ Wq, const float* __restrict__ bq,
                                                  float* __restrict__ ws) {
  int o = blockIdx.x;                       // global output 0..295 (tp*74 + j)
  int k = blockIdx.y * 256 + threadIdx.x;   // 0..767
  int tp = o / 74, j = o - tp * 74;
  float v = (j < 10) ? Wa[k * 40 + tp * 10 + j] : Wq[k * 256 + tp * 64 + (j - 10)];
  ws[WAQT_OFF + (size_t)k * 296 + o] = v;
  if (k == 0) ws[BAQ_OFF + o] = (j < 10) ? ba[tp * 10 + j] : bq[tp * 64 + (j - 10)];
}

// Plain (non-cooperative) launch: flag-spin protocol only; 256 blocks at 1/CU, all
// co-resident (138.75 KB dynamic LDS). R5 topology: 128 LSTM (4 pods x 32) + 128
// tape (n,tp). Weights as in R10 (LDS rows 0..383 + reg/spill rows 384..767).
// NEW (R11): latency-chain pipelining — (1) matvec split around the tflg wait
// (h-part rows 0..511 computed BEFORE polling siblings; only ro-part rows
// 512..767 after), (2) early ro publish (ROB store + RELEASE right after rov,
// before jpos/norm/pos phases), (3) cached lflg skip (no LLC poll when the
// last-seen LSTM flags already cover this step).
__global__ __launch_bounds__(256, 1) void nam_coop(
    const float* __restrict__ Whh, float* __restrict__ ws, float* __restrict__ out)
{
  extern __shared__ __align__(16) char smraw[];
  const int blk = blockIdx.x, tid = threadIdx.x;
  unsigned* lflg = (unsigned*)(ws + LFLG_OFF);
  unsigned* tflg = (unsigned*)(ws + TFLG_OFF);

  if (blk < 128) {
    // ============ LSTM block: pod = blk>>5 (8 batches), 16 dims x 4 gates (R3-R10, proven) ============
    float* hs = (float*)smraw;   // [4096] = pod's 8 h-rows
    const int pod = blk >> 5, c = blk & 31;
    const int ks = tid & 15, cq = tid >> 4;
    const int dg = c * 16 + cq;
    float wG0[32], wG1[32], wG2[32], wG3[32];
#pragma unroll
    for (int j = 0; j < 32; ++j) {
      const float* wr = Whh + (size_t)(j * 16 + ks) * 2048 + dg;
      wG0[j] = wr[0]; wG1[j] = wr[512]; wG2[j] = wr[1024]; wG3[j] = wr[1536];
    }
    const bool fin = (ks == 0);
    float creg[8];
#pragma unroll
    for (int e = 0; e < 8; ++e) creg[e] = 0.f;

    const int wv = tid >> 6, ln = tid & 63;

    for (int t = 0; t < S_LEN; ++t) {
      float gi[32];
      if (fin) {
        const float* gb = ws + GI_OFF + (size_t)t * 65536 + (size_t)dg * 32 + pod * 8;
#pragma unroll
        for (int g = 0; g < 4; ++g) {
          float4 lo = *(const float4*)(gb + (size_t)g * 16384);
          float4 hi = *(const float4*)(gb + (size_t)g * 16384 + 4);
          gi[g * 8 + 0] = lo.x; gi[g * 8 + 1] = lo.y; gi[g * 8 + 2] = lo.z; gi[g * 8 + 3] = lo.w;
          gi[g * 8 + 4] = hi.x; gi[g * 8 + 5] = hi.y; gi[g * 8 + 6] = hi.z; gi[g * 8 + 7] = hi.w;
        }
      }
      if (t > 0) wait_pod(lflg, pod * 32, tid, (unsigned)t);
      __syncthreads();
      {
        const float* hsrc = ws + HTA_OFF + (size_t)t * 16384 + (size_t)pod * 4096
                          + (size_t)wv * 1024 + (size_t)ln * 4;
#pragma unroll
        for (int i = 0; i < 4; ++i)
          ASYNC_LD16(hsrc + i * 256, &hs[wv * 1024 + i * 256]);
      }
      __syncthreads();   // drains vmcnt (async LDS loads)
      float a0[8], a1[8], a2[8], a3[8];
#pragma unroll
      for (int e = 0; e < 8; ++e) { a0[e] = 0.f; a1[e] = 0.f; a2[e] = 0.f; a3[e] = 0.f; }
#pragma unroll
      for (int j = 0; j < 32; ++j) {
        const int kk = j * 16 + ks;
        float w0 = wG0[j], w1 = wG1[j], w2 = wG2[j], w3 = wG3[j];
#pragma unroll
        for (int e = 0; e < 8; ++e) {
          float hv = hs[e * 512 + kk];
          a0[e] = fmaf(hv, w0, a0[e]);
          a1[e] = fmaf(hv, w1, a1[e]);
          a2[e] = fmaf(hv, w2, a2[e]);
          a3[e] = fmaf(hv, w3, a3[e]);
        }
      }
#pragma unroll
      for (int e = 0; e < 8; ++e) {
        float v0 = a0[e], v1 = a1[e], v2 = a2[e], v3 = a3[e];
        v0 += __shfl_down(v0, 8, 16); v1 += __shfl_down(v1, 8, 16);
        v2 += __shfl_down(v2, 8, 16); v3 += __shfl_down(v3, 8, 16);
        v0 += __shfl_down(v0, 4, 16); v1 += __shfl_down(v1, 4, 16);
        v2 += __shfl_down(v2, 4, 16); v3 += __shfl_down(v3, 4, 16);
        v0 += __shfl_down(v0, 2, 16); v1 += __shfl_down(v1, 2, 16);
        v2 += __shfl_down(v2, 2, 16); v3 += __shfl_down(v3, 2, 16);
        v0 += __shfl_down(v0, 1, 16); v1 += __shfl_down(v1, 1, 16);
        v2 += __shfl_down(v2, 1, 16); v3 += __shfl_down(v3, 1, 16);
        a0[e] = v0; a1[e] = v1; a2[e] = v2; a3[e] = v3;
      }
      if (fin) {
        float* hdst = ws + HTA_OFF + (size_t)(t + 1) * 16384 + (size_t)pod * 4096 + dg;
#pragma unroll
        for (int e = 0; e < 8; ++e) {
          float gvi = a0[e] + gi[e];
          float gvf = a1[e] + gi[8 + e];
          float gvg = a2[e] + gi[16 + e];
          float gvo = a3[e] + gi[24 + e];
          float si = 1.f / (1.f + expf(-gvi));
          float sf = 1.f / (1.f + expf(-gvf));
          float so = 1.f / (1.f + expf(-gvo));
          float cn = sf * creg[e] + si * tanhf(gvg);
          float hn = so * tanhf(cn);
          creg[e] = cn;
          coh_st(hdst + (size_t)e * 512, hn);
        }
      }
      __syncthreads();   // h stores vmcnt-drained before flag
      if (tid == 0) coh_stu_rel(lflg + blk * 16, (unsigned)(t + 1));
    }
  } else {
    // ============ tape block: one (n, tp) group (R10 data layout, pipelined control flow) ============
    float* wldsf = (float*)(smraw + L_WLDS);     // [384][74] K-rows 0..383
    float* tape = (float*)(smraw + L_TAPE);
    float* tkey = (float*)(smraw + L_TKEY);
    float* har  = (float*)(smraw + L_HAR);
    float* scrA = (float*)(smraw + L_SCRA);
    float* scrB = (float*)(smraw + L_SCRB);
    float* scrq = (float*)(smraw + L_SCRQ);
    float* rpos = (float*)(smraw + L_RPOS);
    float* wpos = (float*)(smraw + L_WPOS);
    float* actb = (float*)(smraw + L_ACT);
    float* qv   = (float*)(smraw + L_Q);
    float* vvb  = (float*)(smraw + L_V);
    float* krs  = (float*)(smraw + L_KR);
    float* dvs  = (float*)(smraw + L_DV);
    float* dks  = (float*)(smraw + L_DK);
    float* normp= (float*)(smraw + L_NORM);

    const int g = blk - 128, n = g >> 2, tpp = g & 3;
    const int lpodbase = (n >> 3) * 32;
    const int p37 = tid % 37, s6 = tid / 37;     // matvec task: 222 active threads

    // prologue 1: stage K-rows 0..383 of this tape's weight slice into LDS (fp32, once)
    {
      const float* wsrc = ws + WAQT_OFF;
      for (int i = tid; i < 28416; i += 256) {
        int row = i / 74, j = i - row * 74;
        wldsf[i] = wsrc[(size_t)row * 296 + tpp * 74 + j];
      }
    }
    // prologue 2: K-rows 384..767 into registers (64 float2)
    float2 wreg[64];
    if (tid < 222) {
      const float* wb = ws + WAQT_OFF + (size_t)(384 + s6 * 64) * 296 + tpp * 74 + 2 * p37;
#pragma unroll
      for (int r = 0; r < 64; ++r)
        wreg[r] = *(const float2*)(wb + (size_t)r * 296);
    }
    for (int i = tid; i < 2048; i += 256) { tape[i] = 0.f; tkey[i] = 0.f; }
    if (tid < 32) { rpos[tid] = (tid == 0) ? 1.f : 0.f; wpos[tid] = (tid == 0) ? 1.f : 0.f; }
    unsigned lseen = 0;                          // cached last-seen LSTM flag (lanes<64)
    __syncthreads();

    for (int tau = 0; tau < S_LEN; ++tau) {
      // flag-independent prefetch (plain cached)
      float vreg = 0.f, kreg = 0.f;
      if (tid < 64)        vreg = ws[VAL_OFF + (size_t)tau * 8192 + n * 256 + tpp * 64 + tid];
      else if (tid < 128)  kreg = ws[KEY_OFF + (size_t)tau * 8192 + n * 256 + tpp * 64 + (tid - 64)];
      // lflg wait with cached skip (wave 0), then stage h + v (same wave, program order)
      if (tid < 64) {
        unsigned tgt = (unsigned)(tau + 1);
        if (!__all(lseen >= tgt)) {
          const unsigned* fp = lflg + (size_t)(lpodbase + (tid & 31)) * 16;
          while (true) {
            unsigned a = coh_ldu(fp);
            lseen = a;
            if (__all(a >= tgt)) break;
            __builtin_amdgcn_s_sleep(1);
          }
        }
        asm volatile("" ::: "memory");
        const float* hb = ws + HTA_OFF + (size_t)(tau + 1) * 16384 + (size_t)n * 512 + (size_t)tid * 4;
        ASYNC_LD16(hb,       &har[0]);
        ASYNC_LD16(hb + 256, &har[256]);
        vvb[tid] = vreg;
      } else if (tid < 128) {
        krs[tid - 64] = kreg;
      }
      __syncthreads();   // h staged (wave0 drains vmcnt at barrier), v/k in LDS
      // matvec-A: h-dependent part (LDS rows 0..383 all threads; reg rows 384..511 for s6<2)
      float acc0 = 0.f, acc1 = 0.f;
      if (tid < 222) {
        const float2* w2 = (const float2*)wldsf;
        const float* hL = har + s6 * 64;
#pragma unroll
        for (int r = 0; r < 64; ++r) {
          float2 wvp = w2[(s6 * 64 + r) * 37 + p37];
          float h = hL[r];
          acc0 = fmaf(wvp.x, h, acc0);
          acc1 = fmaf(wvp.y, h, acc1);
        }
        if (s6 < 2) {
          const float* hR = har + 384 + s6 * 64;   // rows 384..511 (h)
#pragma unroll
          for (int r = 0; r < 64; ++r) {
            float h = hR[r];
            acc0 = fmaf(wreg[r].x, h, acc0);
            acc1 = fmaf(wreg[r].y, h, acc1);
          }
        }
      }
      // tflg wait (siblings' publish latency overlapped with matvec-A), then stage ro
      if (tid < 64) {
        if (tau > 0) {
          unsigned tgt2 = (unsigned)tau;
          while (true) {
            unsigned a = (tid < 4) ? coh_ldu(tflg + (n * 4 + tid) * 16) : tgt2;
            if (__all(a >= tgt2)) break;
            __builtin_amdgcn_s_sleep(1);
          }
          asm volatile("" ::: "memory");
        }
        const float* rb = ws + ROB_OFF + (size_t)tau * 8192 + (size_t)n * 256 + (size_t)tid * 4;
        ASYNC_LD16(rb, &har[512]);
      }
      __syncthreads();   // ro staged
      // matvec-B: ro-dependent part (reg rows 512..767, s6>=2)
      if (tid < 222) {
        if (s6 >= 2) {
          const float* hR = har + 384 + s6 * 64;   // rows 512..767 (ro)
#pragma unroll
          for (int r = 0; r < 64; ++r) {
            float h = hR[r];
            acc0 = fmaf(wreg[r].x, h, acc0);
            acc1 = fmaf(wreg[r].y, h, acc1);
          }
        }
        scrq[(s6 * 37 + p37) * 2 + 0] = acc0;
        scrq[(s6 * 37 + p37) * 2 + 1] = acc1;
      }
      __syncthreads();
      // reduce 6 K-subs + bias -> act / q   (output o = tid = 2j+half)
      if (tid < 74) {
        int j = tid >> 1, half = tid & 1;
        float sacc = 0.f;
#pragma unroll
        for (int sub = 0; sub < 6; ++sub) sacc += scrq[(sub * 37 + j) * 2 + half];
        float val = sacc + ws[BAQ_OFF + tpp * 74 + tid];
        if (tid < 10) actb[tid] = val; else qv[tid - 10] = val;
      }
      __syncthreads();
      float rd0, rd1, rd2, rd3, wd0, wd1, wd2, wd3, rw0, rw1;
      {
        float a0 = actb[0], a1 = actb[1], a2 = actb[2], a3 = actb[3];
        float mx = fmaxf(fmaxf(a0, a1), fmaxf(a2, a3));
        float e0 = expf(a0 - mx), e1 = expf(a1 - mx), e2 = expf(a2 - mx), e3 = expf(a3 - mx);
        float inv = 1.f / (e0 + e1 + e2 + e3);
        rd0 = e0 * inv; rd1 = e1 * inv; rd2 = e2 * inv; rd3 = e3 * inv;
        a0 = actb[4]; a1 = actb[5]; a2 = actb[6]; a3 = actb[7];
        mx = fmaxf(fmaxf(a0, a1), fmaxf(a2, a3));
        e0 = expf(a0 - mx); e1 = expf(a1 - mx); e2 = expf(a2 - mx); e3 = expf(a3 - mx);
        inv = 1.f / (e0 + e1 + e2 + e3);
        wd0 = e0 * inv; wd1 = e1 * inv; wd2 = e2 * inv; wd3 = e3 * inv;
        rw0 = 1.f / (1.f + expf(-actb[8]));
        rw1 = 1.f / (1.f + expf(-actb[9]));
      }
      const int c = tid & 63, ls = tid >> 6;
      {
        float pv = 0.f, pk = 0.f;
#pragma unroll
        for (int i = 0; i < 8; ++i) {
          int l = ls * 8 + i;
          float wp = wpos[l];
          pv = fmaf(tape[l * 64 + c], wp, pv);
          pk = fmaf(tkey[l * 64 + c], wp, pk);
        }
        scrA[tid] = pv; scrB[tid] = pk;
      }
      __syncthreads();
      if (tid < 64) {
        float ov = scrA[tid] + scrA[tid + 64] + scrA[tid + 128] + scrA[tid + 192];
        float ok = scrB[tid] + scrB[tid + 64] + scrB[tid + 128] + scrB[tid + 192];
        dvs[tid] = (vvb[tid] - ov) * rw1;
        dks[tid] = (krs[tid] - ok) * rw1;
      }
      __syncthreads();
      {
        float pr = 0.f;
        float dvc = dvs[c], dkc = dks[c];
#pragma unroll
        for (int i = 0; i < 8; ++i) {
          int l = ls * 8 + i;
          float wp = wpos[l];
          float tv = tape[l * 64 + c] + wp * dvc;
          tape[l * 64 + c] = tv;
          tkey[l * 64 + c] += wp * dkc;
          pr = fmaf(tv, rpos[l], pr);
        }
        scrA[tid] = pr;
      }
      __syncthreads();
      // rov + EARLY publish: siblings only need ROB data + flag — release it now,
      // before jpos/norm/pos-update. Wave-0-local: RELEASE fence covers its lanes'
      // ROB stores (no barrier needed between store and flag).
      if (tid < 64) {
        float rov = (scrA[tid] + scrA[tid + 64] + scrA[tid + 128] + scrA[tid + 192]) * rw0;
        coh_st(ws + ROB_OFF + (size_t)(tau + 1) * 8192 + n * 256 + tpp * 64 + tid, rov);
      }
      if (tid == 0) coh_stu_rel(tflg + g * 16, (unsigned)(tau + 1));
      // jpos partials (all threads; overlaps wave0's release drain)
      {
        int l2 = tid & 31, cs2 = tid >> 5;
        float pj = 0.f;
#pragma unroll
        for (int i = 0; i < 8; ++i) {
          int cc = cs2 * 8 + i;
          pj = fmaf(tkey[l2 * 64 + cc], qv[cc], pj);
        }
        scrB[tid] = pj;
      }
      __syncthreads();
      float jp = 0.f;
      if (tid < 32) {
#pragma unroll
        for (int cs3 = 0; cs3 < 8; ++cs3) jp += scrB[cs3 * 32 + tid];
      }
      if (tid < 64) {
        float v2 = (tid < 32) ? jp : 0.f;
        float ss = v2 * v2;
#pragma unroll
        for (int off = 32; off > 0; off >>= 1) ss += __shfl_down(ss, off, 64);
        if (tid == 0) normp[0] = fmaxf(sqrtf(ss), 1e-12f);
      }
      __syncthreads();
      if (tid < 32) {
        float jn = jp / normp[0];
        float prv = rpos[(tid + 1) & 31];
        float nxt = rpos[(tid + 31) & 31];
        float rp = rpos[tid], wp = wpos[tid];
        wpos[tid] = prv * wd0 + wp * wd1 + nxt * wd2 + jn * wd3;
        rpos[tid] = prv * rd0 + rp * rd1 + nxt * rd2 + jn * rd3;
      }
      __syncthreads();   // end-of-step: rpos/wpos final before next iteration
    }
    // final tape write-out
    for (int i = tid; i < 2048; i += 256) {
      int l = i >> 6, cc = i & 63;
      out[4194304 + (size_t)(l * 32 + n) * 256 + tpp * 64 + cc] = tape[l * 64 + cc];
    }
  }
}

// out[s][n][d] = sum_m ROB[s+1][n][m] * Wo[m][d] + bo[d]; LDS-transposed ro tile
__global__ __launch_bounds__(256) void k_out_gemm(const float* __restrict__ rob, const float* __restrict__ Wo,
                                                  const float* __restrict__ bo, float* __restrict__ out) {
  __shared__ __align__(16) float ro[256 * 32];   // [m][n], XOR-swizzled float4 chunks over n
  int s = blockIdx.x >> 1, dh = blockIdx.x & 1;
  int d = dh * 256 + threadIdx.x;
  const int tid = threadIdx.x;
  const float* src = rob + (size_t)(s + 1) * 8192;   // slot s+1 = read_outs step s
  for (int w = 0; w < 32; ++w) {
    int idx = tid + w * 256;                 // idx = n*256 + m
    int n = idx >> 8, m = idx & 255;
    float v = src[idx];
    ro[m * 32 + ((((n >> 2) ^ (m & 7)) << 2) | (n & 3))] = v;
  }
  __syncthreads();
  float acc[32];
#pragma unroll
  for (int n = 0; n < 32; ++n) acc[n] = 0.f;
  for (int m = 0; m < 256; ++m) {
    float w = Wo[m * 512 + d];
    const float4* rc = (const float4*)(ro + m * 32);
#pragma unroll
    for (int j = 0; j < 8; ++j) {
      float4 r4 = rc[j ^ (m & 7)];
      acc[4 * j + 0] = fmaf(r4.x, w, acc[4 * j + 0]);
      acc[4 * j + 1] = fmaf(r4.y, w, acc[4 * j + 1]);
      acc[4 * j + 2] = fmaf(r4.z, w, acc[4 * j + 2]);
      acc[4 * j + 3] = fmaf(r4.w, w, acc[4 * j + 3]);
    }
  }
  float bd = bo[d];
#pragma unroll
  for (int n = 0; n < 32; ++n) out[(size_t)(s * 32 + n) * 512 + d] = acc[n] + bd;
}

extern "C" void kernel_launch(void* const* d_in, const int* in_sizes, int n_in,
                              void* d_out, int out_size, void* d_ws, size_t ws_size,
                              hipStream_t stream) {
  const float* inp = (const float*)d_in[0];
  const float* Wih = (const float*)d_in[1];
  const float* Whh = (const float*)d_in[2];
  const float* bih = (const float*)d_in[3];
  const float* bhh = (const float*)d_in[4];
  const float* Wa  = (const float*)d_in[5];
  const float* ba  = (const float*)d_in[6];
  const float* Wv  = (const float*)d_in[7];
  const float* bv  = (const float*)d_in[8];
  const float* Wk  = (const float*)d_in[9];
  const float* bk  = (const float*)d_in[10];
  const float* Wq  = (const float*)d_in[11];
  const float* bq  = (const float*)d_in[12];
  const float* Wo  = (const float*)d_in[13];
  const float* bo  = (const float*)d_in[14];
  float* ws = (float*)d_ws;
  float* out = (float*)d_out;

  // allow >64 KB dynamic LDS (host-side attribute; R8/R10 validated this launches)
  static bool attr_set = false;
  if (!attr_set) {
    hipFuncSetAttribute((const void*)nam_coop,
                        hipFuncAttributeMaxDynamicSharedMemorySize, (int)DYN_LDS);
    attr_set = true;
  }

  hipMemsetAsync(ws + HTA_OFF, 0, 16384 * sizeof(float), stream);    // h_{-1} slot
  hipMemsetAsync(ws + ROB_OFF, 0, 8192 * sizeof(float), stream);     // ro_{-1} slot
  hipMemsetAsync(ws + LFLG_OFF, 0, 4096 * sizeof(unsigned), stream); // LFLG + TFLG
  k_prep_waq<<<dim3(296, 3), 256, 0, stream>>>(Wa, ba, Wq, bq, ws);
  k_pre<<<2560, 256, 0, stream>>>(inp, Wih, bih, bhh, Wv, bv, Wk, bk, ws);
  k_knorm<<<8192, 256, 0, stream>>>(ws);

  // Plain launch — flag-spin protocol only; 256 blocks at 1/CU, all co-resident.
  nam_coop<<<dim3(256), dim3(256), DYN_LDS, stream>>>(Whh, ws, out);

  k_out_gemm<<<512, 256, 0, stream>>>(ws + ROB_OFF, Wo, bo, out);
}